// Round 14
// baseline (228.238 us; speedup 1.0000x reference)
//
#include <hip/hip_runtime.h>
#include <hip/hip_bf16.h>

#define N_NODES 20000
#define N_EDGES 320000
#define IN_DIM 256
#define HID 128
#define HEADS 4
#define MPAD 20096   // 157 * 128

typedef unsigned short u16;
typedef __attribute__((ext_vector_type(8))) short bf16x8;
typedef __attribute__((ext_vector_type(4))) float f32x4;
typedef __attribute__((address_space(1))) void g_void;
typedef __attribute__((address_space(3))) void l_void;

__device__ __forceinline__ float asf(unsigned int u) {
    union { unsigned int i; float f; } c; c.i = u; return c.f;
}
__device__ __forceinline__ float bflo(unsigned int u) { return asf(u << 16); }
__device__ __forceinline__ float bfhi(unsigned int u) { return asf(u & 0xffff0000u); }
__device__ __forceinline__ u16 f2bf(float f) {
    union { float f; unsigned int i; } c; c.f = f;
    return (u16)((c.i + 0x7FFF + ((c.i >> 16) & 1)) >> 16);   // RNE
}
// bijective XCD swizzle (m204)
__device__ __forceinline__ int xcd_swz(int orig, int nwg) {
    int q = nwg >> 3, r = nwg & 7;
    int xcd = orig & 7, lin = orig >> 3;
    return (xcd < r ? xcd * (q + 1) : r * (q + 1) + (xcd - r) * q) + lin;
}

// ---------------------------------------------------------------------------
// CSR build: histogram -> scan -> scatter(eid,dst) -> parallel rank+fill
// Deterministic: final ssrc order within each segment is ascending edge id.
// ---------------------------------------------------------------------------
__global__ void hist_kernel(const int* __restrict__ dst, int* __restrict__ deg, int E) {
    int i = blockIdx.x * blockDim.x + threadIdx.x;
    if (i < E) atomicAdd(&deg[dst[i]], 1);
}

__global__ __launch_bounds__(1024) void scan_kernel(
    const int* __restrict__ deg, int* __restrict__ row_start,
    int* __restrict__ cursor, int n) {
    __shared__ int partial[1024];
    int t = threadIdx.x;
    int chunk = (n + 1023) / 1024;
    int begin = t * chunk;
    int end = min(begin + chunk, n);
    int s = 0;
    for (int i = begin; i < end; ++i) s += deg[i];
    partial[t] = s;
    __syncthreads();
    for (int off = 1; off < 1024; off <<= 1) {
        int v = (t >= off) ? partial[t - off] : 0;
        __syncthreads();
        partial[t] += v;
        __syncthreads();
    }
    int run = (t == 0) ? 0 : partial[t - 1];
    for (int i = begin; i < end; ++i) {
        row_start[i] = run;
        cursor[i] = run;
        run += deg[i];
    }
    if (t == 1023) row_start[n] = run;
}

__global__ void scatter_kernel(const int* __restrict__ dst, int* __restrict__ cursor,
                               int* __restrict__ seid, int* __restrict__ sdst, int E) {
    int i = blockIdx.x * blockDim.x + threadIdx.x;
    if (i < E) {
        int d = dst[i];
        int pos = atomicAdd(&cursor[d], 1);
        seid[pos] = i;
        sdst[pos] = d;
    }
}

__global__ void rank_kernel(const int* __restrict__ row_start, const int* __restrict__ seid,
                            const int* __restrict__ sdst, const int* __restrict__ src,
                            int* __restrict__ ssrc, int E) {
    int i = blockIdx.x * blockDim.x + threadIdx.x;
    if (i >= E) return;
    int d = sdst[i];
    int beg = row_start[d], end = row_start[d + 1];
    int my = seid[i];
    int rank = 0;
    for (int j = beg; j < end; ++j) rank += (seid[j] < my) ? 1 : 0;
    ssrc[beg + rank] = src[my];
}

// ---------------------------------------------------------------------------
// cast x (fp32 [20000][256]) -> bf16 [MPAD][256], pad rows zeroed
// ---------------------------------------------------------------------------
__global__ void cast_x_kernel(const float* __restrict__ x, u16* __restrict__ xb) {
    int i = blockIdx.x * blockDim.x + threadIdx.x;     // quad id
    const int nq = MPAD * IN_DIM / 4;
    if (i >= nq) return;
    int elem = i * 4;
    uint2 u;
    if (elem < N_NODES * IN_DIM) {
        float4 v = ((const float4*)x)[i];
        u.x = (unsigned)f2bf(v.x) | ((unsigned)f2bf(v.y) << 16);
        u.y = (unsigned)f2bf(v.z) | ((unsigned)f2bf(v.w) << 16);
    } else {
        u.x = 0u; u.y = 0u;
    }
    *(uint2*)(xb + elem) = u;
}

// ---------------------------------------------------------------------------
// transpose+cast all four weights: W fp32 [K][N] -> out bf16 [N][K]
// ---------------------------------------------------------------------------
__global__ __launch_bounds__(256) void transpose_all_kernel(
    const float* __restrict__ W1l, const float* __restrict__ W1r,
    const float* __restrict__ W2l, const float* __restrict__ W2r,
    u16* __restrict__ BT1, u16* __restrict__ BT2) {
    const float* W; u16* out; int K, N;
    switch (blockIdx.z) {
        case 0:  W = W1l; out = BT1;             K = 256; N = 512; break;
        case 1:  W = W1r; out = BT1 + 512 * 256; K = 256; N = 512; break;
        case 2:  W = W2l; out = BT2;             K = 512; N = 128; break;
        default: W = W2r; out = BT2 + 128 * 512; K = 512; N = 128; break;
    }
    int bx = blockIdx.x * 32;   // n base
    int by = blockIdx.y * 32;   // k base
    if (bx >= N || by >= K) return;
    __shared__ float t[32][33];
    int tx = threadIdx.x, ty = threadIdx.y;
    #pragma unroll
    for (int j = 0; j < 32; j += 8)
        t[ty + j][tx] = W[(size_t)(by + ty + j) * N + bx + tx];
    __syncthreads();
    #pragma unroll
    for (int j = 0; j < 32; j += 8)
        out[(size_t)(bx + ty + j) * K + by + tx] = f2bf(t[tx][ty + j]);
}

// ---------------------------------------------------------------------------
// concat biases (fp32)
// ---------------------------------------------------------------------------
__global__ void prep_bias_kernel(const float* b1l, const float* b1r,
                                 const float* b2l, const float* b2r,
                                 float* bc1, float* bc2) {
    int t = threadIdx.x;   // one block of 1024
    if (t < 512) bc1[t] = b1l[t];
    else bc1[t] = b1r[t - 512];
    if (t < 128) bc2[t] = b2l[t];
    else if (t < 256) bc2[t] = b2r[t - 128];
}

// ---------------------------------------------------------------------------
// bf16 MFMA GEMM, SPLIT OUTPUT: cols [0,halfN) -> Cl, [halfN,2*halfN) -> Cr,
// each stored [MPAD][halfN]. Tiles are 128 wide and halfN % 128 == 0, so a
// tile maps wholly to one buffer. LDS-staged coalesced epilogue; XCD swizzle.
// ---------------------------------------------------------------------------
__global__ __launch_bounds__(256) void gemm_bf16_kernel(
    const u16* __restrict__ A, const u16* __restrict__ BT,
    const float* __restrict__ bias, u16* __restrict__ Cl, u16* __restrict__ Cr,
    int K, int halfN, int nbx) {
    __shared__ u16 smem[8192];           // As[4096] | Bs[4096]; epilogue: 64x128
    u16* As = smem;
    u16* Bs = smem + 4096;
    const int tid = threadIdx.x;
    const int lane = tid & 63;
    const int wid = tid >> 6;
    const int wr = wid >> 1, wc = wid & 1;
    const int wg = xcd_swz(blockIdx.x, gridDim.x);
    const int brow = (wg / nbx) * 128, bcol = (wg % nbx) * 128;

    const int srow = tid >> 2;
    const int skk = (((tid & 3) ^ ((tid >> 3) & 3))) * 8;
    const u16* ga0 = A + (size_t)(brow + srow) * K + skk;
    const u16* ga1 = A + (size_t)(brow + 64 + srow) * K + skk;
    const u16* gb0 = BT + (size_t)(bcol + srow) * K + skk;
    const u16* gb1 = BT + (size_t)(bcol + 64 + srow) * K + skk;
    u16* lA0 = As + tid * 8;
    u16* lA1 = As + 2048 + tid * 8;
    u16* lB0 = Bs + tid * 8;
    u16* lB1 = Bs + 2048 + tid * 8;

    const int fr = lane & 15;
    const int fg = lane >> 4;
    const int fslot = (fg ^ ((fr >> 1) & 3)) * 8;
    const u16* ra = As + (wr * 64 + fr) * 32 + fslot;
    const u16* rb = Bs + (wc * 64 + fr) * 32 + fslot;

    f32x4 acc[4][4];
    #pragma unroll
    for (int m = 0; m < 4; ++m)
        #pragma unroll
        for (int n = 0; n < 4; ++n)
            acc[m][n] = (f32x4){0.f, 0.f, 0.f, 0.f};

    for (int k0 = 0; k0 < K; k0 += 32) {
        __builtin_amdgcn_global_load_lds((const g_void*)(ga0 + k0), (l_void*)lA0, 16, 0, 0);
        __builtin_amdgcn_global_load_lds((const g_void*)(ga1 + k0), (l_void*)lA1, 16, 0, 0);
        __builtin_amdgcn_global_load_lds((const g_void*)(gb0 + k0), (l_void*)lB0, 16, 0, 0);
        __builtin_amdgcn_global_load_lds((const g_void*)(gb1 + k0), (l_void*)lB1, 16, 0, 0);
        __syncthreads();
        bf16x8 av[4], bv[4];
        #pragma unroll
        for (int m = 0; m < 4; ++m) av[m] = *(const bf16x8*)(ra + m * 512);
        #pragma unroll
        for (int n = 0; n < 4; ++n) bv[n] = *(const bf16x8*)(rb + n * 512);
        #pragma unroll
        for (int m = 0; m < 4; ++m)
            #pragma unroll
            for (int n = 0; n < 4; ++n)
                acc[m][n] = __builtin_amdgcn_mfma_f32_16x16x32_bf16(av[m], bv[n], acc[m][n], 0, 0, 0);
        __syncthreads();
    }

    // output buffer select (whole tile is in one half)
    const bool right = (bcol >= halfN);
    u16* Cb = right ? Cr : Cl;
    const int cbase = bcol - (right ? halfN : 0);

    // epilogue: half-tile LDS repack, then coalesced bf16x8 row stores.
    float bv4[4];
    #pragma unroll
    for (int n = 0; n < 4; ++n) bv4[n] = bias[bcol + wc * 64 + n * 16 + fr];
    #pragma unroll
    for (int ph = 0; ph < 2; ++ph) {
        __syncthreads();
        if (wr == ph) {
            #pragma unroll
            for (int m = 0; m < 4; ++m)
                #pragma unroll
                for (int n = 0; n < 4; ++n) {
                    const int cc = wc * 64 + n * 16 + fr;
                    #pragma unroll
                    for (int j = 0; j < 4; ++j) {
                        const int rr = m * 16 + fg * 4 + j;
                        smem[rr * 128 + (cc ^ (((rr >> 2) & 3) << 4))] =
                            f2bf(acc[m][n][j] + bv4[n]);
                    }
                }
        }
        __syncthreads();
        #pragma unroll
        for (int it = 0; it < 4; ++it) {
            const int rr = it * 16 + (tid >> 4);
            const int cc0 = (tid & 15) * 8;
            *(bf16x8*)(Cb + (size_t)(brow + ph * 64 + rr) * halfN + cbase + cc0) =
                *(const bf16x8*)(smem + rr * 128 + (cc0 ^ (((rr >> 2) & 3) << 4)));
        }
    }
}

// ---------------------------------------------------------------------------
// fused layer-1 edge phase: one wave per node, no-shift softmax, 2-edge
// unroll with dual prefetch. Gathers from dense xl [MPAD][512] buffer.
// ---------------------------------------------------------------------------
#define UNPACK8(c, f) \
    f[0] = bflo(c.x); f[1] = bfhi(c.x); f[2] = bflo(c.y); f[3] = bfhi(c.y); \
    f[4] = bflo(c.z); f[5] = bfhi(c.z); f[6] = bflo(c.w); f[7] = bfhi(c.w);

__global__ __launch_bounds__(256) void fused1_kernel(
    const u16* __restrict__ xl, const u16* __restrict__ xr,
    const int* __restrict__ row_start, const int* __restrict__ ssrc,
    const float* __restrict__ att1, const float* __restrict__ bias1,
    u16* __restrict__ h1, int n) {
    int node = blockIdx.x * 4 + (threadIdx.x >> 6);
    int lane = threadIdx.x & 63;
    if (node >= n) return;

    uint4 xr4 = *(const uint4*)(xr + (size_t)node * 512 + lane * 8);
    float xrf[8];
    UNPACK8(xr4, xrf);
    float4 w0 = ((const float4*)att1)[lane * 2];
    float4 w1 = ((const float4*)att1)[lane * 2 + 1];
    float wa[8] = {w0.x, w0.y, w0.z, w0.w, w1.x, w1.y, w1.z, w1.w};

    int beg = row_start[node], end = row_start[node + 1];
    float l = 0.f;
    float acc[8] = {0.f, 0.f, 0.f, 0.f, 0.f, 0.f, 0.f, 0.f};

    uint4 v0 = {0, 0, 0, 0}, v1 = {0, 0, 0, 0};
    if (beg < end)     v0 = *(const uint4*)(xl + (size_t)ssrc[beg] * 512 + lane * 8);
    if (beg + 1 < end) v1 = *(const uint4*)(xl + (size_t)ssrc[beg + 1] * 512 + lane * 8);

    for (int p = beg; p < end; p += 2) {
        uint4 c0 = v0, c1 = v1;
        if (p + 2 < end) v0 = *(const uint4*)(xl + (size_t)ssrc[p + 2] * 512 + lane * 8);
        if (p + 3 < end) v1 = *(const uint4*)(xl + (size_t)ssrc[p + 3] * 512 + lane * 8);

        float xf[8];
        UNPACK8(c0, xf);
        float sc = 0.f;
        #pragma unroll
        for (int j = 0; j < 8; ++j) {
            float v = xf[j] + xrf[j];
            sc = fmaf(fmaxf(v, 0.2f * v), wa[j], sc);
        }
        sc += __shfl_xor(sc, 1);
        sc += __shfl_xor(sc, 2);
        sc += __shfl_xor(sc, 4);
        sc += __shfl_xor(sc, 8);
        float pv = __expf(sc);
        l += pv;
        #pragma unroll
        for (int j = 0; j < 8; ++j) acc[j] = fmaf(pv, xf[j], acc[j]);

        if (p + 1 < end) {
            float yf[8];
            UNPACK8(c1, yf);
            float sc1 = 0.f;
            #pragma unroll
            for (int j = 0; j < 8; ++j) {
                float v = yf[j] + xrf[j];
                sc1 = fmaf(fmaxf(v, 0.2f * v), wa[j], sc1);
            }
            sc1 += __shfl_xor(sc1, 1);
            sc1 += __shfl_xor(sc1, 2);
            sc1 += __shfl_xor(sc1, 4);
            sc1 += __shfl_xor(sc1, 8);
            float pv1 = __expf(sc1);
            l += pv1;
            #pragma unroll
            for (int j = 0; j < 8; ++j) acc[j] = fmaf(pv1, yf[j], acc[j]);
        }
    }

    float inv = 1.f / (l + 1e-16f);
    float4 b0 = ((const float4*)bias1)[lane * 2];
    float4 b1 = ((const float4*)bias1)[lane * 2 + 1];
    float bb[8] = {b0.x, b0.y, b0.z, b0.w, b1.x, b1.y, b1.z, b1.w};
    bf16x8 outv;
    #pragma unroll
    for (int j = 0; j < 8; ++j) {
        float v = fmaf(acc[j], inv, bb[j]);
        v = v > 0.f ? v : __expf(v) - 1.f;   // ELU
        outv[j] = (short)f2bf(v);
    }
    *(bf16x8*)(h1 + (size_t)node * 512 + lane * 8) = outv;
}

// ---------------------------------------------------------------------------
// fused layer-2 edge phase + heads: one wave per node, no-shift softmax,
// 2-edge unroll. Gathers from dense xl2 [MPAD][128] buffer (~5 MB).
// ---------------------------------------------------------------------------
__global__ __launch_bounds__(256) void fused2_kernel(
    const u16* __restrict__ xl2, const u16* __restrict__ xr2,
    const int* __restrict__ row_start, const int* __restrict__ ssrc,
    const float* __restrict__ att2, const float* __restrict__ bias2,
    const float* __restrict__ Wa, const float* __restrict__ ba,
    const float* __restrict__ Wrc, const float* __restrict__ brc,
    float* __restrict__ out, int n) {
    int node = blockIdx.x * 4 + (threadIdx.x >> 6);
    int lane = threadIdx.x & 63;
    if (node >= n) return;

    unsigned int xr = *(const unsigned int*)(xr2 + (size_t)node * 128 + lane * 2);
    float xr0 = bflo(xr), xr1 = bfhi(xr);
    float2 w = ((const float2*)att2)[lane];

    int beg = row_start[node], end = row_start[node + 1];
    float l = 0.f, acc0 = 0.f, acc1 = 0.f;

    unsigned int v0 = 0, v1 = 0;
    if (beg < end)     v0 = *(const unsigned int*)(xl2 + (size_t)ssrc[beg] * 128 + lane * 2);
    if (beg + 1 < end) v1 = *(const unsigned int*)(xl2 + (size_t)ssrc[beg + 1] * 128 + lane * 2);

    for (int p = beg; p < end; p += 2) {
        unsigned int c0 = v0, c1 = v1;
        if (p + 2 < end) v0 = *(const unsigned int*)(xl2 + (size_t)ssrc[p + 2] * 128 + lane * 2);
        if (p + 3 < end) v1 = *(const unsigned int*)(xl2 + (size_t)ssrc[p + 3] * 128 + lane * 2);

        float x0 = bflo(c0), x1 = bfhi(c0);
        float t0 = x0 + xr0, t1 = x1 + xr1;
        float sc = fmaxf(t0, 0.2f * t0) * w.x + fmaxf(t1, 0.2f * t1) * w.y;
        #pragma unroll
        for (int off = 1; off < 64; off <<= 1) sc += __shfl_xor(sc, off);
        float pv = __expf(sc);
        l += pv;
        acc0 = fmaf(pv, x0, acc0);
        acc1 = fmaf(pv, x1, acc1);

        if (p + 1 < end) {
            float y0 = bflo(c1), y1 = bfhi(c1);
            float u0 = y0 + xr0, u1 = y1 + xr1;
            float sc1 = fmaxf(u0, 0.2f * u0) * w.x + fmaxf(u1, 0.2f * u1) * w.y;
            #pragma unroll
            for (int off = 1; off < 64; off <<= 1) sc1 += __shfl_xor(sc1, off);
            float pv1 = __expf(sc1);
            l += pv1;
            acc0 = fmaf(pv1, y0, acc0);
            acc1 = fmaf(pv1, y1, acc1);
        }
    }

    float inv = 1.f / (l + 1e-16f);
    int c0i = lane * 2, c1i = lane * 2 + 1;
    float h0 = fmaf(acc0, inv, bias2[c0i]);
    float h1v = fmaf(acc1, inv, bias2[c1i]);
    float a = h0 * Wa[c0i] + h1v * Wa[c1i];
    float r = h0 * Wrc[c0i] + h1v * Wrc[c1i];
    #pragma unroll
    for (int off = 1; off < 64; off <<= 1) {
        a += __shfl_xor(a, off);
        r += __shfl_xor(r, off);
    }
    if (lane == 0) {
        out[node]     = 1.f / (1.f + __expf(-(a + ba[0])));
        out[n + node] = 1.f / (1.f + __expf(-(r + brc[0])));
    }
}

// ---------------------------------------------------------------------------
extern "C" void kernel_launch(void* const* d_in, const int* in_sizes, int n_in,
                              void* d_out, int out_size, void* d_ws, size_t ws_size,
                              hipStream_t stream) {
    const float* x    = (const float*)d_in[0];
    const int* ei     = (const int*)d_in[1];
    const float* W1l  = (const float*)d_in[2];
    const float* b1l  = (const float*)d_in[3];
    const float* W1r  = (const float*)d_in[4];
    const float* b1r  = (const float*)d_in[5];
    const float* att1 = (const float*)d_in[6];
    const float* bias1= (const float*)d_in[7];
    const float* W2l  = (const float*)d_in[8];
    const float* b2l  = (const float*)d_in[9];
    const float* W2r  = (const float*)d_in[10];
    const float* b2r  = (const float*)d_in[11];
    const float* att2 = (const float*)d_in[12];
    const float* bias2= (const float*)d_in[13];
    const float* Wa   = (const float*)d_in[14];
    const float* ba   = (const float*)d_in[15];
    const float* Wrc  = (const float*)d_in[16];
    const float* brc  = (const float*)d_in[17];
    float* out = (float*)d_out;

    const int N = N_NODES, E = N_EDGES;
    const int* src = ei;
    const int* dst = ei + E;

    char* ws = (char*)d_ws;
    u16*   xl1  = (u16*)ws;                           // [MPAD][512] bf16 = 20,578,304
    u16*   xr1  = (u16*)(ws + 20578304);              // [MPAD][512] bf16 = 20,578,304
    u16*   h1b  = (u16*)(ws + 41156608);              // [MPAD][512] bf16 = 20,578,304
    u16*   xb   = (u16*)(ws + 61734912);              // [MPAD][256] bf16 = 10,289,152
    u16*   xl2  = (u16*)(ws + 61734912);              // [MPAD][128] reuses xb (gemm2)
    u16*   xr2  = (u16*)(ws + 61734912 + 5144576);    // [MPAD][128]
    u16*   BT1  = (u16*)(ws + 72024064);              // [1024][256] bf16 = 524,288
    u16*   BT2  = (u16*)(ws + 72548352);              // [256][512] bf16 = 262,144
    float* bc1  = (float*)(ws + 72810496);            // 4096
    float* bc2  = (float*)(ws + 72814592);            // 1024
    int* deg       = (int*)(ws + 72815616);           // 80,000
    int* row_start = (int*)(ws + 72896000);           // 80,004
    int* cursor    = (int*)(ws + 72976128);           // 80,000
    int* ssrc      = (int*)(ws + 73056128);           // 1,280,000
    int* seid      = (int*)(ws + 74336128);           // 1,280,000
    int* sdst      = (int*)(ws + 75616128);           // 1,280,000
    // end ~76.9 MB (89.8 MB proven available)

    // --- CSR build (deterministic via parallel rank) ---
    hipMemsetAsync(deg, 0, N * sizeof(int), stream);
    hist_kernel<<<(E + 255) / 256, 256, 0, stream>>>(dst, deg, E);
    scan_kernel<<<1, 1024, 0, stream>>>(deg, row_start, cursor, N);
    scatter_kernel<<<(E + 255) / 256, 256, 0, stream>>>(dst, cursor, seid, sdst, E);
    rank_kernel<<<(E + 255) / 256, 256, 0, stream>>>(row_start, seid, sdst, src, ssrc, E);

    // --- casts / weight prep ---
    cast_x_kernel<<<(MPAD * IN_DIM / 4 + 255) / 256, 256, 0, stream>>>(x, xb);
    transpose_all_kernel<<<dim3(16, 16, 4), dim3(32, 8), 0, stream>>>(
        W1l, W1r, W2l, W2r, BT1, BT2);
    prep_bias_kernel<<<1, 1024, 0, stream>>>(b1l, b1r, b2l, b2r, bc1, bc2);

    // --- layer 1: GEMM writes split xl1|xr1, then fused edge phase ---
    gemm_bf16_kernel<<<157 * 8, 256, 0, stream>>>(xb, BT1, bc1, xl1, xr1, 256, 512, 8);
    fused1_kernel<<<(N + 3) / 4, 256, 0, stream>>>(xl1, xr1, row_start, ssrc,
                                                   att1, bias1, h1b, N);

    // --- layer 2 + heads: GEMM writes split xl2|xr2 ---
    gemm_bf16_kernel<<<157 * 2, 256, 0, stream>>>(h1b, BT2, bc2, xl2, xr2, 512, 128, 2);
    fused2_kernel<<<(N + 3) / 4, 256, 0, stream>>>(xl2, xr2, row_start, ssrc, att2, bias2,
                                                   Wa, ba, Wrc, brc, out, N);
}

// Round 15
// 219.059 us; speedup vs baseline: 1.0419x; 1.0419x over previous
//
#include <hip/hip_runtime.h>
#include <hip/hip_bf16.h>

#define N_NODES 20000
#define N_EDGES 320000
#define IN_DIM 256
#define HID 128
#define HEADS 4
#define MPAD 20096   // 157 * 128

typedef unsigned short u16;
typedef __attribute__((ext_vector_type(8))) short bf16x8;
typedef __attribute__((ext_vector_type(4))) float f32x4;
typedef __attribute__((address_space(1))) void g_void;
typedef __attribute__((address_space(3))) void l_void;

__device__ __forceinline__ float asf(unsigned int u) {
    union { unsigned int i; float f; } c; c.i = u; return c.f;
}
__device__ __forceinline__ float bflo(unsigned int u) { return asf(u << 16); }
__device__ __forceinline__ float bfhi(unsigned int u) { return asf(u & 0xffff0000u); }
__device__ __forceinline__ u16 f2bf(float f) {
    union { float f; unsigned int i; } c; c.f = f;
    return (u16)((c.i + 0x7FFF + ((c.i >> 16) & 1)) >> 16);   // RNE
}
// bijective XCD swizzle (m204)
__device__ __forceinline__ int xcd_swz(int orig, int nwg) {
    int q = nwg >> 3, r = nwg & 7;
    int xcd = orig & 7, lin = orig >> 3;
    return (xcd < r ? xcd * (q + 1) : r * (q + 1) + (xcd - r) * q) + lin;
}

// ---------------------------------------------------------------------------
// CSR build: histogram -> scan -> scatter(eid,dst) -> parallel rank+fill
// Deterministic: final ssrc order within each segment is ascending edge id.
// ---------------------------------------------------------------------------
__global__ void hist_kernel(const int* __restrict__ dst, int* __restrict__ deg, int E) {
    int i = blockIdx.x * blockDim.x + threadIdx.x;
    if (i < E) atomicAdd(&deg[dst[i]], 1);
}

__global__ __launch_bounds__(1024) void scan_kernel(
    const int* __restrict__ deg, int* __restrict__ row_start,
    int* __restrict__ cursor, int n) {
    __shared__ int partial[1024];
    int t = threadIdx.x;
    int chunk = (n + 1023) / 1024;
    int begin = t * chunk;
    int end = min(begin + chunk, n);
    int s = 0;
    for (int i = begin; i < end; ++i) s += deg[i];
    partial[t] = s;
    __syncthreads();
    for (int off = 1; off < 1024; off <<= 1) {
        int v = (t >= off) ? partial[t - off] : 0;
        __syncthreads();
        partial[t] += v;
        __syncthreads();
    }
    int run = (t == 0) ? 0 : partial[t - 1];
    for (int i = begin; i < end; ++i) {
        row_start[i] = run;
        cursor[i] = run;
        run += deg[i];
    }
    if (t == 1023) row_start[n] = run;
}

__global__ void scatter_kernel(const int* __restrict__ dst, int* __restrict__ cursor,
                               int* __restrict__ seid, int* __restrict__ sdst, int E) {
    int i = blockIdx.x * blockDim.x + threadIdx.x;
    if (i < E) {
        int d = dst[i];
        int pos = atomicAdd(&cursor[d], 1);
        seid[pos] = i;
        sdst[pos] = d;
    }
}

__global__ void rank_kernel(const int* __restrict__ row_start, const int* __restrict__ seid,
                            const int* __restrict__ sdst, const int* __restrict__ src,
                            int* __restrict__ ssrc, int E) {
    int i = blockIdx.x * blockDim.x + threadIdx.x;
    if (i >= E) return;
    int d = sdst[i];
    int beg = row_start[d], end = row_start[d + 1];
    int my = seid[i];
    int rank = 0;
    for (int j = beg; j < end; ++j) rank += (seid[j] < my) ? 1 : 0;
    ssrc[beg + rank] = src[my];
}

// ---------------------------------------------------------------------------
// cast x (fp32 [20000][256]) -> bf16 [MPAD][256], pad rows zeroed
// ---------------------------------------------------------------------------
__global__ void cast_x_kernel(const float* __restrict__ x, u16* __restrict__ xb) {
    int i = blockIdx.x * blockDim.x + threadIdx.x;     // quad id
    const int nq = MPAD * IN_DIM / 4;
    if (i >= nq) return;
    int elem = i * 4;
    uint2 u;
    if (elem < N_NODES * IN_DIM) {
        float4 v = ((const float4*)x)[i];
        u.x = (unsigned)f2bf(v.x) | ((unsigned)f2bf(v.y) << 16);
        u.y = (unsigned)f2bf(v.z) | ((unsigned)f2bf(v.w) << 16);
    } else {
        u.x = 0u; u.y = 0u;
    }
    *(uint2*)(xb + elem) = u;
}

// ---------------------------------------------------------------------------
// transpose+cast all four weights: W fp32 [K][N] -> out bf16 [N][K]
// ---------------------------------------------------------------------------
__global__ __launch_bounds__(256) void transpose_all_kernel(
    const float* __restrict__ W1l, const float* __restrict__ W1r,
    const float* __restrict__ W2l, const float* __restrict__ W2r,
    u16* __restrict__ BT1, u16* __restrict__ BT2) {
    const float* W; u16* out; int K, N;
    switch (blockIdx.z) {
        case 0:  W = W1l; out = BT1;             K = 256; N = 512; break;
        case 1:  W = W1r; out = BT1 + 512 * 256; K = 256; N = 512; break;
        case 2:  W = W2l; out = BT2;             K = 512; N = 128; break;
        default: W = W2r; out = BT2 + 128 * 512; K = 512; N = 128; break;
    }
    int bx = blockIdx.x * 32;   // n base
    int by = blockIdx.y * 32;   // k base
    if (bx >= N || by >= K) return;
    __shared__ float t[32][33];
    int tx = threadIdx.x, ty = threadIdx.y;
    #pragma unroll
    for (int j = 0; j < 32; j += 8)
        t[ty + j][tx] = W[(size_t)(by + ty + j) * N + bx + tx];
    __syncthreads();
    #pragma unroll
    for (int j = 0; j < 32; j += 8)
        out[(size_t)(bx + ty + j) * K + by + tx] = f2bf(t[tx][ty + j]);
}

// ---------------------------------------------------------------------------
// concat biases (fp32)
// ---------------------------------------------------------------------------
__global__ void prep_bias_kernel(const float* b1l, const float* b1r,
                                 const float* b2l, const float* b2r,
                                 float* bc1, float* bc2) {
    int t = threadIdx.x;   // one block of 1024
    if (t < 512) bc1[t] = b1l[t];
    else bc1[t] = b1r[t - 512];
    if (t < 128) bc2[t] = b2l[t];
    else if (t < 256) bc2[t] = b2r[t - 128];
}

// ---------------------------------------------------------------------------
// bf16 MFMA GEMM, SPLIT OUTPUT: cols [0,halfN) -> Cl, [halfN,2*halfN) -> Cr,
// each stored [MPAD][halfN]. Tiles are 128 wide and halfN % 128 == 0, so a
// tile maps wholly to one buffer. LDS-staged coalesced epilogue; XCD swizzle.
// ---------------------------------------------------------------------------
__global__ __launch_bounds__(256) void gemm_bf16_kernel(
    const u16* __restrict__ A, const u16* __restrict__ BT,
    const float* __restrict__ bias, u16* __restrict__ Cl, u16* __restrict__ Cr,
    int K, int halfN, int nbx) {
    __shared__ u16 smem[8192];           // As[4096] | Bs[4096]; epilogue: 64x128
    u16* As = smem;
    u16* Bs = smem + 4096;
    const int tid = threadIdx.x;
    const int lane = tid & 63;
    const int wid = tid >> 6;
    const int wr = wid >> 1, wc = wid & 1;
    const int wg = xcd_swz(blockIdx.x, gridDim.x);
    const int brow = (wg / nbx) * 128, bcol = (wg % nbx) * 128;

    const int srow = tid >> 2;
    const int skk = (((tid & 3) ^ ((tid >> 3) & 3))) * 8;
    const u16* ga0 = A + (size_t)(brow + srow) * K + skk;
    const u16* ga1 = A + (size_t)(brow + 64 + srow) * K + skk;
    const u16* gb0 = BT + (size_t)(bcol + srow) * K + skk;
    const u16* gb1 = BT + (size_t)(bcol + 64 + srow) * K + skk;
    u16* lA0 = As + tid * 8;
    u16* lA1 = As + 2048 + tid * 8;
    u16* lB0 = Bs + tid * 8;
    u16* lB1 = Bs + 2048 + tid * 8;

    const int fr = lane & 15;
    const int fg = lane >> 4;
    const int fslot = (fg ^ ((fr >> 1) & 3)) * 8;
    const u16* ra = As + (wr * 64 + fr) * 32 + fslot;
    const u16* rb = Bs + (wc * 64 + fr) * 32 + fslot;

    f32x4 acc[4][4];
    #pragma unroll
    for (int m = 0; m < 4; ++m)
        #pragma unroll
        for (int n = 0; n < 4; ++n)
            acc[m][n] = (f32x4){0.f, 0.f, 0.f, 0.f};

    for (int k0 = 0; k0 < K; k0 += 32) {
        __builtin_amdgcn_global_load_lds((const g_void*)(ga0 + k0), (l_void*)lA0, 16, 0, 0);
        __builtin_amdgcn_global_load_lds((const g_void*)(ga1 + k0), (l_void*)lA1, 16, 0, 0);
        __builtin_amdgcn_global_load_lds((const g_void*)(gb0 + k0), (l_void*)lB0, 16, 0, 0);
        __builtin_amdgcn_global_load_lds((const g_void*)(gb1 + k0), (l_void*)lB1, 16, 0, 0);
        __syncthreads();
        bf16x8 av[4], bv[4];
        #pragma unroll
        for (int m = 0; m < 4; ++m) av[m] = *(const bf16x8*)(ra + m * 512);
        #pragma unroll
        for (int n = 0; n < 4; ++n) bv[n] = *(const bf16x8*)(rb + n * 512);
        #pragma unroll
        for (int m = 0; m < 4; ++m)
            #pragma unroll
            for (int n = 0; n < 4; ++n)
                acc[m][n] = __builtin_amdgcn_mfma_f32_16x16x32_bf16(av[m], bv[n], acc[m][n], 0, 0, 0);
        __syncthreads();
    }

    // output buffer select (whole tile is in one half)
    const bool right = (bcol >= halfN);
    u16* Cb = right ? Cr : Cl;
    const int cbase = bcol - (right ? halfN : 0);

    // epilogue: half-tile LDS repack, then coalesced bf16x8 row stores.
    float bv4[4];
    #pragma unroll
    for (int n = 0; n < 4; ++n) bv4[n] = bias[bcol + wc * 64 + n * 16 + fr];
    #pragma unroll
    for (int ph = 0; ph < 2; ++ph) {
        __syncthreads();
        if (wr == ph) {
            #pragma unroll
            for (int m = 0; m < 4; ++m)
                #pragma unroll
                for (int n = 0; n < 4; ++n) {
                    const int cc = wc * 64 + n * 16 + fr;
                    #pragma unroll
                    for (int j = 0; j < 4; ++j) {
                        const int rr = m * 16 + fg * 4 + j;
                        smem[rr * 128 + (cc ^ (((rr >> 2) & 3) << 4))] =
                            f2bf(acc[m][n][j] + bv4[n]);
                    }
                }
        }
        __syncthreads();
        #pragma unroll
        for (int it = 0; it < 4; ++it) {
            const int rr = it * 16 + (tid >> 4);
            const int cc0 = (tid & 15) * 8;
            *(bf16x8*)(Cb + (size_t)(brow + ph * 64 + rr) * halfN + cbase + cc0) =
                *(const bf16x8*)(smem + rr * 128 + (cc0 ^ (((rr >> 2) & 3) << 4)));
        }
    }
}

// ---------------------------------------------------------------------------
// fused layer-1 edge phase: one wave per node, no-shift softmax, 2-edge
// unroll with dual prefetch (measured-best form). Dense xl [MPAD][512].
// ---------------------------------------------------------------------------
#define UNPACK8(c, f) \
    f[0] = bflo(c.x); f[1] = bfhi(c.x); f[2] = bflo(c.y); f[3] = bfhi(c.y); \
    f[4] = bflo(c.z); f[5] = bfhi(c.z); f[6] = bflo(c.w); f[7] = bfhi(c.w);

__global__ __launch_bounds__(256) void fused1_kernel(
    const u16* __restrict__ xl, const u16* __restrict__ xr,
    const int* __restrict__ row_start, const int* __restrict__ ssrc,
    const float* __restrict__ att1, const float* __restrict__ bias1,
    u16* __restrict__ h1, int n) {
    int node = blockIdx.x * 4 + (threadIdx.x >> 6);
    int lane = threadIdx.x & 63;
    if (node >= n) return;

    uint4 xr4 = *(const uint4*)(xr + (size_t)node * 512 + lane * 8);
    float xrf[8];
    UNPACK8(xr4, xrf);
    float4 w0 = ((const float4*)att1)[lane * 2];
    float4 w1 = ((const float4*)att1)[lane * 2 + 1];
    float wa[8] = {w0.x, w0.y, w0.z, w0.w, w1.x, w1.y, w1.z, w1.w};

    int beg = row_start[node], end = row_start[node + 1];
    float l = 0.f;
    float acc[8] = {0.f, 0.f, 0.f, 0.f, 0.f, 0.f, 0.f, 0.f};

    uint4 v0 = {0, 0, 0, 0}, v1 = {0, 0, 0, 0};
    if (beg < end)     v0 = *(const uint4*)(xl + (size_t)ssrc[beg] * 512 + lane * 8);
    if (beg + 1 < end) v1 = *(const uint4*)(xl + (size_t)ssrc[beg + 1] * 512 + lane * 8);

    for (int p = beg; p < end; p += 2) {
        uint4 c0 = v0, c1 = v1;
        if (p + 2 < end) v0 = *(const uint4*)(xl + (size_t)ssrc[p + 2] * 512 + lane * 8);
        if (p + 3 < end) v1 = *(const uint4*)(xl + (size_t)ssrc[p + 3] * 512 + lane * 8);

        float xf[8];
        UNPACK8(c0, xf);
        float sc = 0.f;
        #pragma unroll
        for (int j = 0; j < 8; ++j) {
            float v = xf[j] + xrf[j];
            sc = fmaf(fmaxf(v, 0.2f * v), wa[j], sc);
        }
        sc += __shfl_xor(sc, 1);
        sc += __shfl_xor(sc, 2);
        sc += __shfl_xor(sc, 4);
        sc += __shfl_xor(sc, 8);
        float pv = __expf(sc);
        l += pv;
        #pragma unroll
        for (int j = 0; j < 8; ++j) acc[j] = fmaf(pv, xf[j], acc[j]);

        if (p + 1 < end) {
            float yf[8];
            UNPACK8(c1, yf);
            float sc1 = 0.f;
            #pragma unroll
            for (int j = 0; j < 8; ++j) {
                float v = yf[j] + xrf[j];
                sc1 = fmaf(fmaxf(v, 0.2f * v), wa[j], sc1);
            }
            sc1 += __shfl_xor(sc1, 1);
            sc1 += __shfl_xor(sc1, 2);
            sc1 += __shfl_xor(sc1, 4);
            sc1 += __shfl_xor(sc1, 8);
            float pv1 = __expf(sc1);
            l += pv1;
            #pragma unroll
            for (int j = 0; j < 8; ++j) acc[j] = fmaf(pv1, yf[j], acc[j]);
        }
    }

    float inv = 1.f / (l + 1e-16f);
    float4 b0 = ((const float4*)bias1)[lane * 2];
    float4 b1 = ((const float4*)bias1)[lane * 2 + 1];
    float bb[8] = {b0.x, b0.y, b0.z, b0.w, b1.x, b1.y, b1.z, b1.w};
    bf16x8 outv;
    #pragma unroll
    for (int j = 0; j < 8; ++j) {
        float v = fmaf(acc[j], inv, bb[j]);
        v = v > 0.f ? v : __expf(v) - 1.f;   // ELU
        outv[j] = (short)f2bf(v);
    }
    *(bf16x8*)(h1 + (size_t)node * 512 + lane * 8) = outv;
}

// ---------------------------------------------------------------------------
// fused layer-2 edge phase + heads: one wave per node, no-shift softmax,
// 4-edge BRANCHLESS unroll (measured-best in r12: 4 independent 6-deep shfl
// chains in flight, 1 uint state/edge so no VGPR penalty). Clamped-index
// loads; invalid edges neutralized via pv=0. Sequential summation order.
// ---------------------------------------------------------------------------
__global__ __launch_bounds__(256) void fused2_kernel(
    const u16* __restrict__ xl2, const u16* __restrict__ xr2,
    const int* __restrict__ row_start, const int* __restrict__ ssrc,
    const float* __restrict__ att2, const float* __restrict__ bias2,
    const float* __restrict__ Wa, const float* __restrict__ ba,
    const float* __restrict__ Wrc, const float* __restrict__ brc,
    float* __restrict__ out, int n) {
    const int node = blockIdx.x * 4 + (threadIdx.x >> 6);
    const int lane = threadIdx.x & 63;
    if (node >= n) return;

    unsigned int xr = *(const unsigned int*)(xr2 + (size_t)node * 128 + lane * 2);
    float xr0 = bflo(xr), xr1 = bfhi(xr);
    float2 w = ((const float2*)att2)[lane];

    const int beg = row_start[node], end = row_start[node + 1];
    float l = 0.f, acc0 = 0.f, acc1 = 0.f;

    if (beg < end) {
        const int last = end - 1;
        unsigned int c[4];
        #pragma unroll
        for (int k = 0; k < 4; ++k)
            c[k] = *(const unsigned int*)(xl2 + (size_t)ssrc[min(beg + k, last)] * 128 + lane * 2);

        for (int p = beg; p < end; p += 4) {
            unsigned int nx[4];
            #pragma unroll
            for (int k = 0; k < 4; ++k)
                nx[k] = *(const unsigned int*)(xl2 + (size_t)ssrc[min(p + 4 + k, last)] * 128 + lane * 2);

            float x0[4], x1[4], sc[4];
            #pragma unroll
            for (int k = 0; k < 4; ++k) {
                x0[k] = bflo(c[k]); x1[k] = bfhi(c[k]);
                float t0 = x0[k] + xr0, t1 = x1[k] + xr1;
                sc[k] = fmaxf(t0, 0.2f * t0) * w.x + fmaxf(t1, 0.2f * t1) * w.y;
            }
            #pragma unroll
            for (int k = 0; k < 4; ++k) {
                #pragma unroll
                for (int off = 1; off < 64; off <<= 1) sc[k] += __shfl_xor(sc[k], off);
            }
            #pragma unroll
            for (int k = 0; k < 4; ++k) {
                float pv = (p + k < end) ? __expf(sc[k]) : 0.f;
                l += pv;
                acc0 = fmaf(pv, x0[k], acc0);
                acc1 = fmaf(pv, x1[k], acc1);
            }
            #pragma unroll
            for (int k = 0; k < 4; ++k) c[k] = nx[k];
        }
    }

    float inv = 1.f / (l + 1e-16f);
    int c0i = lane * 2, c1i = lane * 2 + 1;
    float h0 = fmaf(acc0, inv, bias2[c0i]);
    float h1v = fmaf(acc1, inv, bias2[c1i]);
    float a = h0 * Wa[c0i] + h1v * Wa[c1i];
    float r = h0 * Wrc[c0i] + h1v * Wrc[c1i];
    #pragma unroll
    for (int off = 1; off < 64; off <<= 1) {
        a += __shfl_xor(a, off);
        r += __shfl_xor(r, off);
    }
    if (lane == 0) {
        out[node]     = 1.f / (1.f + __expf(-(a + ba[0])));
        out[n + node] = 1.f / (1.f + __expf(-(r + brc[0])));
    }
}

// ---------------------------------------------------------------------------
extern "C" void kernel_launch(void* const* d_in, const int* in_sizes, int n_in,
                              void* d_out, int out_size, void* d_ws, size_t ws_size,
                              hipStream_t stream) {
    const float* x    = (const float*)d_in[0];
    const int* ei     = (const int*)d_in[1];
    const float* W1l  = (const float*)d_in[2];
    const float* b1l  = (const float*)d_in[3];
    const float* W1r  = (const float*)d_in[4];
    const float* b1r  = (const float*)d_in[5];
    const float* att1 = (const float*)d_in[6];
    const float* bias1= (const float*)d_in[7];
    const float* W2l  = (const float*)d_in[8];
    const float* b2l  = (const float*)d_in[9];
    const float* W2r  = (const float*)d_in[10];
    const float* b2r  = (const float*)d_in[11];
    const float* att2 = (const float*)d_in[12];
    const float* bias2= (const float*)d_in[13];
    const float* Wa   = (const float*)d_in[14];
    const float* ba   = (const float*)d_in[15];
    const float* Wrc  = (const float*)d_in[16];
    const float* brc  = (const float*)d_in[17];
    float* out = (float*)d_out;

    const int N = N_NODES, E = N_EDGES;
    const int* src = ei;
    const int* dst = ei + E;

    char* ws = (char*)d_ws;
    u16*   xl1  = (u16*)ws;                           // [MPAD][512] bf16 = 20,578,304
    u16*   xr1  = (u16*)(ws + 20578304);              // [MPAD][512] bf16 = 20,578,304
    u16*   h1b  = (u16*)(ws + 41156608);              // [MPAD][512] bf16 = 20,578,304
    u16*   xb   = (u16*)(ws + 61734912);              // [MPAD][256] bf16 = 10,289,152
    u16*   xl2  = (u16*)(ws + 61734912);              // [MPAD][128] reuses xb (gemm2)
    u16*   xr2  = (u16*)(ws + 61734912 + 5144576);    // [MPAD][128]
    u16*   BT1  = (u16*)(ws + 72024064);              // [1024][256] bf16 = 524,288
    u16*   BT2  = (u16*)(ws + 72548352);              // [256][512] bf16 = 262,144
    float* bc1  = (float*)(ws + 72810496);            // 4096
    float* bc2  = (float*)(ws + 72814592);            // 1024
    int* deg       = (int*)(ws + 72815616);           // 80,000
    int* row_start = (int*)(ws + 72896000);           // 80,004
    int* cursor    = (int*)(ws + 72976128);           // 80,000
    int* ssrc      = (int*)(ws + 73056128);           // 1,280,000
    int* seid      = (int*)(ws + 74336128);           // 1,280,000
    int* sdst      = (int*)(ws + 75616128);           // 1,280,000
    // end ~76.9 MB (89.8 MB proven available)

    // --- CSR build (deterministic via parallel rank) ---
    hipMemsetAsync(deg, 0, N * sizeof(int), stream);
    hist_kernel<<<(E + 255) / 256, 256, 0, stream>>>(dst, deg, E);
    scan_kernel<<<1, 1024, 0, stream>>>(deg, row_start, cursor, N);
    scatter_kernel<<<(E + 255) / 256, 256, 0, stream>>>(dst, cursor, seid, sdst, E);
    rank_kernel<<<(E + 255) / 256, 256, 0, stream>>>(row_start, seid, sdst, src, ssrc, E);

    // --- casts / weight prep ---
    cast_x_kernel<<<(MPAD * IN_DIM / 4 + 255) / 256, 256, 0, stream>>>(x, xb);
    transpose_all_kernel<<<dim3(16, 16, 4), dim3(32, 8), 0, stream>>>(
        W1l, W1r, W2l, W2r, BT1, BT2);
    prep_bias_kernel<<<1, 1024, 0, stream>>>(b1l, b1r, b2l, b2r, bc1, bc2);

    // --- layer 1: GEMM writes split xl1|xr1, then fused edge phase ---
    gemm_bf16_kernel<<<157 * 8, 256, 0, stream>>>(xb, BT1, bc1, xl1, xr1, 256, 512, 8);
    fused1_kernel<<<(N + 3) / 4, 256, 0, stream>>>(xl1, xr1, row_start, ssrc,
                                                   att1, bias1, h1b, N);

    // --- layer 2 + heads: GEMM writes split xl2|xr2 ---
    gemm_bf16_kernel<<<157 * 2, 256, 0, stream>>>(h1b, BT2, bc2, xl2, xr2, 512, 128, 2);
    fused2_kernel<<<(N + 3) / 4, 256, 0, stream>>>(xl2, xr2, row_start, ssrc, att2, bias2,
                                                   Wa, ba, Wrc, brc, out, N);
}

// Round 16
// 218.507 us; speedup vs baseline: 1.0445x; 1.0025x over previous
//
#include <hip/hip_runtime.h>
#include <hip/hip_bf16.h>
#include <hip/hip_fp16.h>

#define N_NODES 20000
#define N_EDGES 320000
#define IN_DIM 256
#define HID 128
#define HEADS 4
#define MPAD 20096   // 157 * 128

typedef unsigned short u16;
typedef _Float16 f16;
typedef __attribute__((ext_vector_type(2))) _Float16 f16x2;
typedef __attribute__((ext_vector_type(8))) _Float16 f16x8;
typedef __attribute__((ext_vector_type(4))) float f32x4;
typedef __attribute__((address_space(1))) void g_void;
typedef __attribute__((address_space(3))) void l_void;

__device__ __forceinline__ u16 f2h16(float f) {
    union { f16 h; u16 u; } c; c.h = (f16)f; return c.u;   // v_cvt_f16_f32, RNE
}
// bijective XCD swizzle (m204)
__device__ __forceinline__ int xcd_swz(int orig, int nwg) {
    int q = nwg >> 3, r = nwg & 7;
    int xcd = orig & 7, lin = orig >> 3;
    return (xcd < r ? xcd * (q + 1) : r * (q + 1) + (xcd - r) * q) + lin;
}

// ---------------------------------------------------------------------------
// CSR build: histogram -> scan -> scatter(eid,dst) -> parallel rank+fill
// Deterministic: final ssrc order within each segment is ascending edge id.
// ---------------------------------------------------------------------------
__global__ void hist_kernel(const int* __restrict__ dst, int* __restrict__ deg, int E) {
    int i = blockIdx.x * blockDim.x + threadIdx.x;
    if (i < E) atomicAdd(&deg[dst[i]], 1);
}

__global__ __launch_bounds__(1024) void scan_kernel(
    const int* __restrict__ deg, int* __restrict__ row_start,
    int* __restrict__ cursor, int n) {
    __shared__ int partial[1024];
    int t = threadIdx.x;
    int chunk = (n + 1023) / 1024;
    int begin = t * chunk;
    int end = min(begin + chunk, n);
    int s = 0;
    for (int i = begin; i < end; ++i) s += deg[i];
    partial[t] = s;
    __syncthreads();
    for (int off = 1; off < 1024; off <<= 1) {
        int v = (t >= off) ? partial[t - off] : 0;
        __syncthreads();
        partial[t] += v;
        __syncthreads();
    }
    int run = (t == 0) ? 0 : partial[t - 1];
    for (int i = begin; i < end; ++i) {
        row_start[i] = run;
        cursor[i] = run;
        run += deg[i];
    }
    if (t == 1023) row_start[n] = run;
}

__global__ void scatter_kernel(const int* __restrict__ dst, int* __restrict__ cursor,
                               int* __restrict__ seid, int* __restrict__ sdst, int E) {
    int i = blockIdx.x * blockDim.x + threadIdx.x;
    if (i < E) {
        int d = dst[i];
        int pos = atomicAdd(&cursor[d], 1);
        seid[pos] = i;
        sdst[pos] = d;
    }
}

__global__ void rank_kernel(const int* __restrict__ row_start, const int* __restrict__ seid,
                            const int* __restrict__ sdst, const int* __restrict__ src,
                            int* __restrict__ ssrc, int E) {
    int i = blockIdx.x * blockDim.x + threadIdx.x;
    if (i >= E) return;
    int d = sdst[i];
    int beg = row_start[d], end = row_start[d + 1];
    int my = seid[i];
    int rank = 0;
    for (int j = beg; j < end; ++j) rank += (seid[j] < my) ? 1 : 0;
    ssrc[beg + rank] = src[my];
}

// ---------------------------------------------------------------------------
// cast x (fp32 [20000][256]) -> f16 [MPAD][256], pad rows zeroed
// ---------------------------------------------------------------------------
__global__ void cast_x_kernel(const float* __restrict__ x, u16* __restrict__ xb) {
    int i = blockIdx.x * blockDim.x + threadIdx.x;     // quad id
    const int nq = MPAD * IN_DIM / 4;
    if (i >= nq) return;
    int elem = i * 4;
    uint2 u;
    if (elem < N_NODES * IN_DIM) {
        float4 v = ((const float4*)x)[i];
        u.x = (unsigned)f2h16(v.x) | ((unsigned)f2h16(v.y) << 16);
        u.y = (unsigned)f2h16(v.z) | ((unsigned)f2h16(v.w) << 16);
    } else {
        u.x = 0u; u.y = 0u;
    }
    *(uint2*)(xb + elem) = u;
}

// ---------------------------------------------------------------------------
// transpose+cast all four weights: W fp32 [K][N] -> out f16 [N][K]
// ---------------------------------------------------------------------------
__global__ __launch_bounds__(256) void transpose_all_kernel(
    const float* __restrict__ W1l, const float* __restrict__ W1r,
    const float* __restrict__ W2l, const float* __restrict__ W2r,
    u16* __restrict__ BT1, u16* __restrict__ BT2) {
    const float* W; u16* out; int K, N;
    switch (blockIdx.z) {
        case 0:  W = W1l; out = BT1;             K = 256; N = 512; break;
        case 1:  W = W1r; out = BT1 + 512 * 256; K = 256; N = 512; break;
        case 2:  W = W2l; out = BT2;             K = 512; N = 128; break;
        default: W = W2r; out = BT2 + 128 * 512; K = 512; N = 128; break;
    }
    int bx = blockIdx.x * 32;   // n base
    int by = blockIdx.y * 32;   // k base
    if (bx >= N || by >= K) return;
    __shared__ float t[32][33];
    int tx = threadIdx.x, ty = threadIdx.y;
    #pragma unroll
    for (int j = 0; j < 32; j += 8)
        t[ty + j][tx] = W[(size_t)(by + ty + j) * N + bx + tx];
    __syncthreads();
    #pragma unroll
    for (int j = 0; j < 32; j += 8)
        out[(size_t)(bx + ty + j) * K + by + tx] = f2h16(t[tx][ty + j]);
}

// ---------------------------------------------------------------------------
// concat biases (fp32)
// ---------------------------------------------------------------------------
__global__ void prep_bias_kernel(const float* b1l, const float* b1r,
                                 const float* b2l, const float* b2r,
                                 float* bc1, float* bc2) {
    int t = threadIdx.x;   // one block of 1024
    if (t < 512) bc1[t] = b1l[t];
    else bc1[t] = b1r[t - 512];
    if (t < 128) bc2[t] = b2l[t];
    else if (t < 256) bc2[t] = b2r[t - 128];
}

// ---------------------------------------------------------------------------
// f16 MFMA GEMM, SPLIT OUTPUT: cols [0,halfN) -> Cl, [halfN,2*halfN) -> Cr,
// each stored [MPAD][halfN]. mfma_f32_16x16x32_f16 (same C/D layout as bf16).
// LDS-staged coalesced epilogue; XCD swizzle.
// ---------------------------------------------------------------------------
__global__ __launch_bounds__(256) void gemm_f16_kernel(
    const u16* __restrict__ A, const u16* __restrict__ BT,
    const float* __restrict__ bias, u16* __restrict__ Cl, u16* __restrict__ Cr,
    int K, int halfN, int nbx) {
    __shared__ u16 smem[8192];           // As[4096] | Bs[4096]; epilogue: 64x128
    u16* As = smem;
    u16* Bs = smem + 4096;
    const int tid = threadIdx.x;
    const int lane = tid & 63;
    const int wid = tid >> 6;
    const int wr = wid >> 1, wc = wid & 1;
    const int wg = xcd_swz(blockIdx.x, gridDim.x);
    const int brow = (wg / nbx) * 128, bcol = (wg % nbx) * 128;

    const int srow = tid >> 2;
    const int skk = (((tid & 3) ^ ((tid >> 3) & 3))) * 8;
    const u16* ga0 = A + (size_t)(brow + srow) * K + skk;
    const u16* ga1 = A + (size_t)(brow + 64 + srow) * K + skk;
    const u16* gb0 = BT + (size_t)(bcol + srow) * K + skk;
    const u16* gb1 = BT + (size_t)(bcol + 64 + srow) * K + skk;
    u16* lA0 = As + tid * 8;
    u16* lA1 = As + 2048 + tid * 8;
    u16* lB0 = Bs + tid * 8;
    u16* lB1 = Bs + 2048 + tid * 8;

    const int fr = lane & 15;
    const int fg = lane >> 4;
    const int fslot = (fg ^ ((fr >> 1) & 3)) * 8;
    const u16* ra = As + (wr * 64 + fr) * 32 + fslot;
    const u16* rb = Bs + (wc * 64 + fr) * 32 + fslot;

    f32x4 acc[4][4];
    #pragma unroll
    for (int m = 0; m < 4; ++m)
        #pragma unroll
        for (int n = 0; n < 4; ++n)
            acc[m][n] = (f32x4){0.f, 0.f, 0.f, 0.f};

    for (int k0 = 0; k0 < K; k0 += 32) {
        __builtin_amdgcn_global_load_lds((const g_void*)(ga0 + k0), (l_void*)lA0, 16, 0, 0);
        __builtin_amdgcn_global_load_lds((const g_void*)(ga1 + k0), (l_void*)lA1, 16, 0, 0);
        __builtin_amdgcn_global_load_lds((const g_void*)(gb0 + k0), (l_void*)lB0, 16, 0, 0);
        __builtin_amdgcn_global_load_lds((const g_void*)(gb1 + k0), (l_void*)lB1, 16, 0, 0);
        __syncthreads();
        f16x8 av[4], bv[4];
        #pragma unroll
        for (int m = 0; m < 4; ++m) av[m] = *(const f16x8*)(ra + m * 512);
        #pragma unroll
        for (int n = 0; n < 4; ++n) bv[n] = *(const f16x8*)(rb + n * 512);
        #pragma unroll
        for (int m = 0; m < 4; ++m)
            #pragma unroll
            for (int n = 0; n < 4; ++n)
                acc[m][n] = __builtin_amdgcn_mfma_f32_16x16x32_f16(av[m], bv[n], acc[m][n], 0, 0, 0);
        __syncthreads();
    }

    // output buffer select (whole tile is in one half)
    const bool right = (bcol >= halfN);
    u16* Cb = right ? Cr : Cl;
    const int cbase = bcol - (right ? halfN : 0);

    // epilogue: half-tile LDS repack, then coalesced 16B row stores.
    float bv4[4];
    #pragma unroll
    for (int n = 0; n < 4; ++n) bv4[n] = bias[bcol + wc * 64 + n * 16 + fr];
    #pragma unroll
    for (int ph = 0; ph < 2; ++ph) {
        __syncthreads();
        if (wr == ph) {
            #pragma unroll
            for (int m = 0; m < 4; ++m)
                #pragma unroll
                for (int n = 0; n < 4; ++n) {
                    const int cc = wc * 64 + n * 16 + fr;
                    #pragma unroll
                    for (int j = 0; j < 4; ++j) {
                        const int rr = m * 16 + fg * 4 + j;
                        smem[rr * 128 + (cc ^ (((rr >> 2) & 3) << 4))] =
                            f2h16(acc[m][n][j] + bv4[n]);
                    }
                }
        }
        __syncthreads();
        #pragma unroll
        for (int it = 0; it < 4; ++it) {
            const int rr = it * 16 + (tid >> 4);
            const int cc0 = (tid & 15) * 8;
            *(uint4*)(Cb + (size_t)(brow + ph * 64 + rr) * halfN + cbase + cc0) =
                *(const uint4*)(smem + rr * 128 + (cc0 ^ (((rr >> 2) & 3) << 4)));
        }
    }
}

// ---------------------------------------------------------------------------
// fused layer-1 edge phase: one wave per node, no-shift softmax, 2-edge
// unroll with dual prefetch. f16 packed math: v_pk_add/mul/max + fdot2 for
// the score (2 ch/op); fp32 accumulation (exp range needs f32).
// ---------------------------------------------------------------------------
__global__ __launch_bounds__(256) void fused1_kernel(
    const u16* __restrict__ xl, const u16* __restrict__ xr,
    const int* __restrict__ row_start, const int* __restrict__ ssrc,
    const float* __restrict__ att1, const float* __restrict__ bias1,
    u16* __restrict__ h1, int n) {
    int node = blockIdx.x * 4 + (threadIdx.x >> 6);
    int lane = threadIdx.x & 63;
    if (node >= n) return;

    f16x8 xrv = *(const f16x8*)(xr + (size_t)node * 512 + lane * 8);
    const f16x2* xrh = (const f16x2*)&xrv;
    float4 w0 = ((const float4*)att1)[lane * 2];
    float4 w1 = ((const float4*)att1)[lane * 2 + 1];
    f16x2 wa2[4];
    wa2[0] = (f16x2){(f16)w0.x, (f16)w0.y};
    wa2[1] = (f16x2){(f16)w0.z, (f16)w0.w};
    wa2[2] = (f16x2){(f16)w1.x, (f16)w1.y};
    wa2[3] = (f16x2){(f16)w1.z, (f16)w1.w};
    const f16x2 c02 = {(f16)0.2f, (f16)0.2f};

    int beg = row_start[node], end = row_start[node + 1];
    float l = 0.f;
    float acc[8] = {0.f, 0.f, 0.f, 0.f, 0.f, 0.f, 0.f, 0.f};

    f16x8 v0 = {}, v1 = {};
    if (beg < end)     v0 = *(const f16x8*)(xl + (size_t)ssrc[beg] * 512 + lane * 8);
    if (beg + 1 < end) v1 = *(const f16x8*)(xl + (size_t)ssrc[beg + 1] * 512 + lane * 8);

    for (int p = beg; p < end; p += 2) {
        f16x8 c0 = v0, c1 = v1;
        if (p + 2 < end) v0 = *(const f16x8*)(xl + (size_t)ssrc[p + 2] * 512 + lane * 8);
        if (p + 3 < end) v1 = *(const f16x8*)(xl + (size_t)ssrc[p + 3] * 512 + lane * 8);

        const f16x2* xh = (const f16x2*)&c0;
        float sc = 0.f;
        #pragma unroll
        for (int j = 0; j < 4; ++j) {
            f16x2 v = xh[j] + xrh[j];
            f16x2 lr = __builtin_elementwise_max(v, v * c02);
            sc = __builtin_amdgcn_fdot2(lr, wa2[j], sc, false);
        }
        sc += __shfl_xor(sc, 1);
        sc += __shfl_xor(sc, 2);
        sc += __shfl_xor(sc, 4);
        sc += __shfl_xor(sc, 8);
        float pv = __expf(sc);
        l += pv;
        #pragma unroll
        for (int j = 0; j < 8; ++j) acc[j] = fmaf(pv, (float)c0[j], acc[j]);

        if (p + 1 < end) {
            const f16x2* yh = (const f16x2*)&c1;
            float sc1 = 0.f;
            #pragma unroll
            for (int j = 0; j < 4; ++j) {
                f16x2 v = yh[j] + xrh[j];
                f16x2 lr = __builtin_elementwise_max(v, v * c02);
                sc1 = __builtin_amdgcn_fdot2(lr, wa2[j], sc1, false);
            }
            sc1 += __shfl_xor(sc1, 1);
            sc1 += __shfl_xor(sc1, 2);
            sc1 += __shfl_xor(sc1, 4);
            sc1 += __shfl_xor(sc1, 8);
            float pv1 = __expf(sc1);
            l += pv1;
            #pragma unroll
            for (int j = 0; j < 8; ++j) acc[j] = fmaf(pv1, (float)c1[j], acc[j]);
        }
    }

    float inv = 1.f / (l + 1e-16f);
    float4 b0 = ((const float4*)bias1)[lane * 2];
    float4 b1 = ((const float4*)bias1)[lane * 2 + 1];
    float bb[8] = {b0.x, b0.y, b0.z, b0.w, b1.x, b1.y, b1.z, b1.w};
    u16 outb[8];
    #pragma unroll
    for (int j = 0; j < 8; ++j) {
        float v = fmaf(acc[j], inv, bb[j]);
        v = v > 0.f ? v : __expf(v) - 1.f;   // ELU
        outb[j] = f2h16(v);
    }
    *(uint4*)(h1 + (size_t)node * 512 + lane * 8) = *(const uint4*)outb;
}

// ---------------------------------------------------------------------------
// fused layer-2 edge phase + heads: one wave per node, no-shift softmax,
// 4-edge BRANCHLESS unroll (4 independent 6-deep shfl chains in flight).
// f16 packed score; fp32 accumulation; heads + sigmoid in epilogue.
// ---------------------------------------------------------------------------
__global__ __launch_bounds__(256) void fused2_kernel(
    const u16* __restrict__ xl2, const u16* __restrict__ xr2,
    const int* __restrict__ row_start, const int* __restrict__ ssrc,
    const float* __restrict__ att2, const float* __restrict__ bias2,
    const float* __restrict__ Wa, const float* __restrict__ ba,
    const float* __restrict__ Wrc, const float* __restrict__ brc,
    float* __restrict__ out, int n) {
    const int node = blockIdx.x * 4 + (threadIdx.x >> 6);
    const int lane = threadIdx.x & 63;
    if (node >= n) return;

    union uh { unsigned int u; f16x2 h; };
    uh xru; xru.u = *(const unsigned int*)(xr2 + (size_t)node * 128 + lane * 2);
    float2 wf = ((const float2*)att2)[lane];
    const f16x2 w2 = {(f16)wf.x, (f16)wf.y};
    const f16x2 c02 = {(f16)0.2f, (f16)0.2f};

    const int beg = row_start[node], end = row_start[node + 1];
    float l = 0.f, acc0 = 0.f, acc1 = 0.f;

    if (beg < end) {
        const int last = end - 1;
        uh c[4];
        #pragma unroll
        for (int k = 0; k < 4; ++k)
            c[k].u = *(const unsigned int*)(xl2 + (size_t)ssrc[min(beg + k, last)] * 128 + lane * 2);

        for (int p = beg; p < end; p += 4) {
            uh nx[4];
            #pragma unroll
            for (int k = 0; k < 4; ++k)
                nx[k].u = *(const unsigned int*)(xl2 + (size_t)ssrc[min(p + 4 + k, last)] * 128 + lane * 2);

            float sc[4];
            #pragma unroll
            for (int k = 0; k < 4; ++k) {
                f16x2 v = c[k].h + xru.h;
                f16x2 lr = __builtin_elementwise_max(v, v * c02);
                sc[k] = __builtin_amdgcn_fdot2(lr, w2, 0.f, false);
            }
            #pragma unroll
            for (int k = 0; k < 4; ++k) {
                #pragma unroll
                for (int off = 1; off < 64; off <<= 1) sc[k] += __shfl_xor(sc[k], off);
            }
            #pragma unroll
            for (int k = 0; k < 4; ++k) {
                float pv = (p + k < end) ? __expf(sc[k]) : 0.f;
                l += pv;
                acc0 = fmaf(pv, (float)c[k].h[0], acc0);
                acc1 = fmaf(pv, (float)c[k].h[1], acc1);
            }
            #pragma unroll
            for (int k = 0; k < 4; ++k) c[k] = nx[k];
        }
    }

    float inv = 1.f / (l + 1e-16f);
    int c0i = lane * 2, c1i = lane * 2 + 1;
    float h0 = fmaf(acc0, inv, bias2[c0i]);
    float h1v = fmaf(acc1, inv, bias2[c1i]);
    float a = h0 * Wa[c0i] + h1v * Wa[c1i];
    float r = h0 * Wrc[c0i] + h1v * Wrc[c1i];
    #pragma unroll
    for (int off = 1; off < 64; off <<= 1) {
        a += __shfl_xor(a, off);
        r += __shfl_xor(r, off);
    }
    if (lane == 0) {
        out[node]     = 1.f / (1.f + __expf(-(a + ba[0])));
        out[n + node] = 1.f / (1.f + __expf(-(r + brc[0])));
    }
}

// ---------------------------------------------------------------------------
extern "C" void kernel_launch(void* const* d_in, const int* in_sizes, int n_in,
                              void* d_out, int out_size, void* d_ws, size_t ws_size,
                              hipStream_t stream) {
    const float* x    = (const float*)d_in[0];
    const int* ei     = (const int*)d_in[1];
    const float* W1l  = (const float*)d_in[2];
    const float* b1l  = (const float*)d_in[3];
    const float* W1r  = (const float*)d_in[4];
    const float* b1r  = (const float*)d_in[5];
    const float* att1 = (const float*)d_in[6];
    const float* bias1= (const float*)d_in[7];
    const float* W2l  = (const float*)d_in[8];
    const float* b2l  = (const float*)d_in[9];
    const float* W2r  = (const float*)d_in[10];
    const float* b2r  = (const float*)d_in[11];
    const float* att2 = (const float*)d_in[12];
    const float* bias2= (const float*)d_in[13];
    const float* Wa   = (const float*)d_in[14];
    const float* ba   = (const float*)d_in[15];
    const float* Wrc  = (const float*)d_in[16];
    const float* brc  = (const float*)d_in[17];
    float* out = (float*)d_out;

    const int N = N_NODES, E = N_EDGES;
    const int* src = ei;
    const int* dst = ei + E;

    char* ws = (char*)d_ws;
    u16*   xl1  = (u16*)ws;                           // [MPAD][512] f16 = 20,578,304
    u16*   xr1  = (u16*)(ws + 20578304);              // [MPAD][512] f16 = 20,578,304
    u16*   h1b  = (u16*)(ws + 41156608);              // [MPAD][512] f16 = 20,578,304
    u16*   xb   = (u16*)(ws + 61734912);              // [MPAD][256] f16 = 10,289,152
    u16*   xl2  = (u16*)(ws + 61734912);              // [MPAD][128] reuses xb (gemm2)
    u16*   xr2  = (u16*)(ws + 61734912 + 5144576);    // [MPAD][128]
    u16*   BT1  = (u16*)(ws + 72024064);              // [1024][256] f16 = 524,288
    u16*   BT2  = (u16*)(ws + 72548352);              // [256][512] f16 = 262,144
    float* bc1  = (float*)(ws + 72810496);            // 4096
    float* bc2  = (float*)(ws + 72814592);            // 1024
    int* deg       = (int*)(ws + 72815616);           // 80,000
    int* row_start = (int*)(ws + 72896000);           // 80,004
    int* cursor    = (int*)(ws + 72976128);           // 80,000
    int* ssrc      = (int*)(ws + 73056128);           // 1,280,000
    int* seid      = (int*)(ws + 74336128);           // 1,280,000
    int* sdst      = (int*)(ws + 75616128);           // 1,280,000
    // end ~76.9 MB (89.8 MB proven available)

    // --- CSR build (deterministic via parallel rank) ---
    hipMemsetAsync(deg, 0, N * sizeof(int), stream);
    hist_kernel<<<(E + 255) / 256, 256, 0, stream>>>(dst, deg, E);
    scan_kernel<<<1, 1024, 0, stream>>>(deg, row_start, cursor, N);
    scatter_kernel<<<(E + 255) / 256, 256, 0, stream>>>(dst, cursor, seid, sdst, E);
    rank_kernel<<<(E + 255) / 256, 256, 0, stream>>>(row_start, seid, sdst, src, ssrc, E);

    // --- casts / weight prep ---
    cast_x_kernel<<<(MPAD * IN_DIM / 4 + 255) / 256, 256, 0, stream>>>(x, xb);
    transpose_all_kernel<<<dim3(16, 16, 4), dim3(32, 8), 0, stream>>>(
        W1l, W1r, W2l, W2r, BT1, BT2);
    prep_bias_kernel<<<1, 1024, 0, stream>>>(b1l, b1r, b2l, b2r, bc1, bc2);

    // --- layer 1: GEMM writes split xl1|xr1, then fused edge phase ---
    gemm_f16_kernel<<<157 * 8, 256, 0, stream>>>(xb, BT1, bc1, xl1, xr1, 256, 512, 8);
    fused1_kernel<<<(N + 3) / 4, 256, 0, stream>>>(xl1, xr1, row_start, ssrc,
                                                   att1, bias1, h1b, N);

    // --- layer 2 + heads: GEMM writes split xl2|xr2 ---
    gemm_f16_kernel<<<157 * 2, 256, 0, stream>>>(h1b, BT2, bc2, xl2, xr2, 512, 128, 2);
    fused2_kernel<<<(N + 3) / 4, 256, 0, stream>>>(xl2, xr2, row_start, ssrc, att2, bias2,
                                                   Wa, ba, Wrc, brc, out, N);
}

// Round 20
// 218.379 us; speedup vs baseline: 1.0451x; 1.0006x over previous
//
#include <hip/hip_runtime.h>
#include <hip/hip_bf16.h>
#include <hip/hip_fp16.h>

#define N_NODES 20000
#define N_EDGES 320000
#define IN_DIM 256
#define HID 128
#define HEADS 4
#define MPAD 20096   // 157 * 128

typedef unsigned short u16;
typedef _Float16 f16;
typedef __attribute__((ext_vector_type(2))) _Float16 f16x2;
typedef __attribute__((ext_vector_type(8))) _Float16 f16x8;
typedef __attribute__((ext_vector_type(4))) float f32x4;
typedef __attribute__((address_space(1))) void g_void;
typedef __attribute__((address_space(3))) void l_void;

__device__ __forceinline__ u16 f2h16(float f) {
    union { f16 h; u16 u; } c; c.h = (f16)f; return c.u;   // v_cvt_f16_f32, RNE
}
// bijective XCD swizzle (m204)
__device__ __forceinline__ int xcd_swz(int orig, int nwg) {
    int q = nwg >> 3, r = nwg & 7;
    int xcd = orig & 7, lin = orig >> 3;
    return (xcd < r ? xcd * (q + 1) : r * (q + 1) + (xcd - r) * q) + lin;
}

// ---------------------------------------------------------------------------
// CSR build: histogram -> scan -> scatter(eid,dst) -> parallel rank+fill
// Deterministic: final ssrc order within each segment is ascending edge id.
// ---------------------------------------------------------------------------
__global__ void hist_kernel(const int* __restrict__ dst, int* __restrict__ deg, int E) {
    int i = blockIdx.x * blockDim.x + threadIdx.x;
    if (i < E) atomicAdd(&deg[dst[i]], 1);
}

__global__ __launch_bounds__(1024) void scan_kernel(
    const int* __restrict__ deg, int* __restrict__ row_start,
    int* __restrict__ cursor, int n) {
    __shared__ int partial[1024];
    int t = threadIdx.x;
    int chunk = (n + 1023) / 1024;
    int begin = t * chunk;
    int end = min(begin + chunk, n);
    int s = 0;
    for (int i = begin; i < end; ++i) s += deg[i];
    partial[t] = s;
    __syncthreads();
    for (int off = 1; off < 1024; off <<= 1) {
        int v = (t >= off) ? partial[t - off] : 0;
        __syncthreads();
        partial[t] += v;
        __syncthreads();
    }
    int run = (t == 0) ? 0 : partial[t - 1];
    for (int i = begin; i < end; ++i) {
        row_start[i] = run;
        cursor[i] = run;
        run += deg[i];
    }
    if (t == 1023) row_start[n] = run;
}

__global__ void scatter_kernel(const int* __restrict__ dst, int* __restrict__ cursor,
                               int* __restrict__ seid, int* __restrict__ sdst, int E) {
    int i = blockIdx.x * blockDim.x + threadIdx.x;
    if (i < E) {
        int d = dst[i];
        int pos = atomicAdd(&cursor[d], 1);
        seid[pos] = i;
        sdst[pos] = d;
    }
}

__global__ void rank_kernel(const int* __restrict__ row_start, const int* __restrict__ seid,
                            const int* __restrict__ sdst, const int* __restrict__ src,
                            int* __restrict__ ssrc, int E) {
    int i = blockIdx.x * blockDim.x + threadIdx.x;
    if (i >= E) return;
    int d = sdst[i];
    int beg = row_start[d], end = row_start[d + 1];
    int my = seid[i];
    int rank = 0;
    for (int j = beg; j < end; ++j) rank += (seid[j] < my) ? 1 : 0;
    ssrc[beg + rank] = src[my];
}

// ---------------------------------------------------------------------------
// cast x (fp32 [20000][256]) -> f16 [MPAD][256], pad rows zeroed
// ---------------------------------------------------------------------------
__global__ void cast_x_kernel(const float* __restrict__ x, u16* __restrict__ xb) {
    int i = blockIdx.x * blockDim.x + threadIdx.x;     // quad id
    const int nq = MPAD * IN_DIM / 4;
    if (i >= nq) return;
    int elem = i * 4;
    uint2 u;
    if (elem < N_NODES * IN_DIM) {
        float4 v = ((const float4*)x)[i];
        u.x = (unsigned)f2h16(v.x) | ((unsigned)f2h16(v.y) << 16);
        u.y = (unsigned)f2h16(v.z) | ((unsigned)f2h16(v.w) << 16);
    } else {
        u.x = 0u; u.y = 0u;
    }
    *(uint2*)(xb + elem) = u;
}

// ---------------------------------------------------------------------------
// transpose+cast all four weights: W fp32 [K][N] -> out f16 [N][K]
// ---------------------------------------------------------------------------
__global__ __launch_bounds__(256) void transpose_all_kernel(
    const float* __restrict__ W1l, const float* __restrict__ W1r,
    const float* __restrict__ W2l, const float* __restrict__ W2r,
    u16* __restrict__ BT1, u16* __restrict__ BT2) {
    const float* W; u16* out; int K, N;
    switch (blockIdx.z) {
        case 0:  W = W1l; out = BT1;             K = 256; N = 512; break;
        case 1:  W = W1r; out = BT1 + 512 * 256; K = 256; N = 512; break;
        case 2:  W = W2l; out = BT2;             K = 512; N = 128; break;
        default: W = W2r; out = BT2 + 128 * 512; K = 512; N = 128; break;
    }
    int bx = blockIdx.x * 32;   // n base
    int by = blockIdx.y * 32;   // k base
    if (bx >= N || by >= K) return;
    __shared__ float t[32][33];
    int tx = threadIdx.x, ty = threadIdx.y;
    #pragma unroll
    for (int j = 0; j < 32; j += 8)
        t[ty + j][tx] = W[(size_t)(by + ty + j) * N + bx + tx];
    __syncthreads();
    #pragma unroll
    for (int j = 0; j < 32; j += 8)
        out[(size_t)(bx + ty + j) * K + by + tx] = f2h16(t[tx][ty + j]);
}

// ---------------------------------------------------------------------------
// concat biases (fp32)
// ---------------------------------------------------------------------------
__global__ void prep_bias_kernel(const float* b1l, const float* b1r,
                                 const float* b2l, const float* b2r,
                                 float* bc1, float* bc2) {
    int t = threadIdx.x;   // one block of 1024
    if (t < 512) bc1[t] = b1l[t];
    else bc1[t] = b1r[t - 512];
    if (t < 128) bc2[t] = b2l[t];
    else if (t < 256) bc2[t] = b2r[t - 128];
}

// ---------------------------------------------------------------------------
// f16 MFMA GEMM, SPLIT OUTPUT: cols [0,halfN) -> Cl, [halfN,2*halfN) -> Cr,
// each stored [MPAD][halfN]. mfma_f32_16x16x32_f16 (same C/D layout as bf16).
// LDS-staged coalesced epilogue; XCD swizzle.
// ---------------------------------------------------------------------------
__global__ __launch_bounds__(256) void gemm_f16_kernel(
    const u16* __restrict__ A, const u16* __restrict__ BT,
    const float* __restrict__ bias, u16* __restrict__ Cl, u16* __restrict__ Cr,
    int K, int halfN, int nbx) {
    __shared__ u16 smem[8192];           // As[4096] | Bs[4096]; epilogue: 64x128
    u16* As = smem;
    u16* Bs = smem + 4096;
    const int tid = threadIdx.x;
    const int lane = tid & 63;
    const int wid = tid >> 6;
    const int wr = wid >> 1, wc = wid & 1;
    const int wg = xcd_swz(blockIdx.x, gridDim.x);
    const int brow = (wg / nbx) * 128, bcol = (wg % nbx) * 128;

    const int srow = tid >> 2;
    const int skk = (((tid & 3) ^ ((tid >> 3) & 3))) * 8;
    const u16* ga0 = A + (size_t)(brow + srow) * K + skk;
    const u16* ga1 = A + (size_t)(brow + 64 + srow) * K + skk;
    const u16* gb0 = BT + (size_t)(bcol + srow) * K + skk;
    const u16* gb1 = BT + (size_t)(bcol + 64 + srow) * K + skk;
    u16* lA0 = As + tid * 8;
    u16* lA1 = As + 2048 + tid * 8;
    u16* lB0 = Bs + tid * 8;
    u16* lB1 = Bs + 2048 + tid * 8;

    const int fr = lane & 15;
    const int fg = lane >> 4;
    const int fslot = (fg ^ ((fr >> 1) & 3)) * 8;
    const u16* ra = As + (wr * 64 + fr) * 32 + fslot;
    const u16* rb = Bs + (wc * 64 + fr) * 32 + fslot;

    f32x4 acc[4][4];
    #pragma unroll
    for (int m = 0; m < 4; ++m)
        #pragma unroll
        for (int n = 0; n < 4; ++n)
            acc[m][n] = (f32x4){0.f, 0.f, 0.f, 0.f};

    for (int k0 = 0; k0 < K; k0 += 32) {
        __builtin_amdgcn_global_load_lds((const g_void*)(ga0 + k0), (l_void*)lA0, 16, 0, 0);
        __builtin_amdgcn_global_load_lds((const g_void*)(ga1 + k0), (l_void*)lA1, 16, 0, 0);
        __builtin_amdgcn_global_load_lds((const g_void*)(gb0 + k0), (l_void*)lB0, 16, 0, 0);
        __builtin_amdgcn_global_load_lds((const g_void*)(gb1 + k0), (l_void*)lB1, 16, 0, 0);
        __syncthreads();
        f16x8 av[4], bv[4];
        #pragma unroll
        for (int m = 0; m < 4; ++m) av[m] = *(const f16x8*)(ra + m * 512);
        #pragma unroll
        for (int n = 0; n < 4; ++n) bv[n] = *(const f16x8*)(rb + n * 512);
        #pragma unroll
        for (int m = 0; m < 4; ++m)
            #pragma unroll
            for (int n = 0; n < 4; ++n)
                acc[m][n] = __builtin_amdgcn_mfma_f32_16x16x32_f16(av[m], bv[n], acc[m][n], 0, 0, 0);
        __syncthreads();
    }

    // output buffer select (whole tile is in one half)
    const bool right = (bcol >= halfN);
    u16* Cb = right ? Cr : Cl;
    const int cbase = bcol - (right ? halfN : 0);

    // epilogue: half-tile LDS repack, then coalesced 16B row stores.
    float bv4[4];
    #pragma unroll
    for (int n = 0; n < 4; ++n) bv4[n] = bias[bcol + wc * 64 + n * 16 + fr];
    #pragma unroll
    for (int ph = 0; ph < 2; ++ph) {
        __syncthreads();
        if (wr == ph) {
            #pragma unroll
            for (int m = 0; m < 4; ++m)
                #pragma unroll
                for (int n = 0; n < 4; ++n) {
                    const int cc = wc * 64 + n * 16 + fr;
                    #pragma unroll
                    for (int j = 0; j < 4; ++j) {
                        const int rr = m * 16 + fg * 4 + j;
                        smem[rr * 128 + (cc ^ (((rr >> 2) & 3) << 4))] =
                            f2h16(acc[m][n][j] + bv4[n]);
                    }
                }
        }
        __syncthreads();
        #pragma unroll
        for (int it = 0; it < 4; ++it) {
            const int rr = it * 16 + (tid >> 4);
            const int cc0 = (tid & 15) * 8;
            *(uint4*)(Cb + (size_t)(brow + ph * 64 + rr) * halfN + cbase + cc0) =
                *(const uint4*)(smem + rr * 128 + (cc0 ^ (((rr >> 2) & 3) << 4)));
        }
    }
}

// ---------------------------------------------------------------------------
// fused layer-1 edge phase: one wave per node, no-shift softmax, 4-edge
// BRANCHLESS unroll (f16 packed state: 4 VGPR/edge in flight, no unpack
// arrays). Clamped indices, pv=0 neutralization, sequential sum order.
// Score via v_pk_add/mul/max + fdot2; fp32 accumulation.
// ---------------------------------------------------------------------------
__global__ __launch_bounds__(256) void fused1_kernel(
    const u16* __restrict__ xl, const u16* __restrict__ xr,
    const int* __restrict__ row_start, const int* __restrict__ ssrc,
    const float* __restrict__ att1, const float* __restrict__ bias1,
    u16* __restrict__ h1, int n) {
    int node = blockIdx.x * 4 + (threadIdx.x >> 6);
    int lane = threadIdx.x & 63;
    if (node >= n) return;

    f16x8 xrv = *(const f16x8*)(xr + (size_t)node * 512 + lane * 8);
    const f16x2* xrh = (const f16x2*)&xrv;
    float4 w0 = ((const float4*)att1)[lane * 2];
    float4 w1 = ((const float4*)att1)[lane * 2 + 1];
    f16x2 wa2[4];
    wa2[0] = (f16x2){(f16)w0.x, (f16)w0.y};
    wa2[1] = (f16x2){(f16)w0.z, (f16)w0.w};
    wa2[2] = (f16x2){(f16)w1.x, (f16)w1.y};
    wa2[3] = (f16x2){(f16)w1.z, (f16)w1.w};
    const f16x2 c02 = {(f16)0.2f, (f16)0.2f};

    int beg = row_start[node], end = row_start[node + 1];
    float l = 0.f;
    float acc[8] = {0.f, 0.f, 0.f, 0.f, 0.f, 0.f, 0.f, 0.f};

    if (beg < end) {
        const int last = end - 1;
        f16x8 c[4];
        #pragma unroll
        for (int k = 0; k < 4; ++k)
            c[k] = *(const f16x8*)(xl + (size_t)ssrc[min(beg + k, last)] * 512 + lane * 8);

        for (int p = beg; p < end; p += 4) {
            f16x8 nx[4];
            #pragma unroll
            for (int k = 0; k < 4; ++k)
                nx[k] = *(const f16x8*)(xl + (size_t)ssrc[min(p + 4 + k, last)] * 512 + lane * 8);

            float sc[4];
            #pragma unroll
            for (int k = 0; k < 4; ++k) {
                const f16x2* xh = (const f16x2*)&c[k];
                float s = 0.f;
                #pragma unroll
                for (int j = 0; j < 4; ++j) {
                    f16x2 v = xh[j] + xrh[j];
                    f16x2 lr = __builtin_elementwise_max(v, v * c02);
                    s = __builtin_amdgcn_fdot2(lr, wa2[j], s, false);
                }
                sc[k] = s;
            }
            #pragma unroll
            for (int k = 0; k < 4; ++k) {
                sc[k] += __shfl_xor(sc[k], 1);
                sc[k] += __shfl_xor(sc[k], 2);
                sc[k] += __shfl_xor(sc[k], 4);
                sc[k] += __shfl_xor(sc[k], 8);
            }
            #pragma unroll
            for (int k = 0; k < 4; ++k) {
                float pv = (p + k < end) ? __expf(sc[k]) : 0.f;
                l += pv;
                #pragma unroll
                for (int j = 0; j < 8; ++j) acc[j] = fmaf(pv, (float)c[k][j], acc[j]);
            }
            #pragma unroll
            for (int k = 0; k < 4; ++k) c[k] = nx[k];
        }
    }

    float inv = 1.f / (l + 1e-16f);
    float4 b0 = ((const float4*)bias1)[lane * 2];
    float4 b1 = ((const float4*)bias1)[lane * 2 + 1];
    float bb[8] = {b0.x, b0.y, b0.z, b0.w, b1.x, b1.y, b1.z, b1.w};
    u16 outb[8];
    #pragma unroll
    for (int j = 0; j < 8; ++j) {
        float v = fmaf(acc[j], inv, bb[j]);
        v = v > 0.f ? v : __expf(v) - 1.f;   // ELU
        outb[j] = f2h16(v);
    }
    *(uint4*)(h1 + (size_t)node * 512 + lane * 8) = *(const uint4*)outb;
}

// ---------------------------------------------------------------------------
// fused layer-2 edge phase + heads: one wave per node, no-shift softmax,
// 4-edge BRANCHLESS unroll (4 independent 6-deep shfl chains in flight).
// f16 packed score; fp32 accumulation; heads + sigmoid in epilogue.
// ---------------------------------------------------------------------------
__global__ __launch_bounds__(256) void fused2_kernel(
    const u16* __restrict__ xl2, const u16* __restrict__ xr2,
    const int* __restrict__ row_start, const int* __restrict__ ssrc,
    const float* __restrict__ att2, const float* __restrict__ bias2,
    const float* __restrict__ Wa, const float* __restrict__ ba,
    const float* __restrict__ Wrc, const float* __restrict__ brc,
    float* __restrict__ out, int n) {
    const int node = blockIdx.x * 4 + (threadIdx.x >> 6);
    const int lane = threadIdx.x & 63;
    if (node >= n) return;

    union uh { unsigned int u; f16x2 h; };
    uh xru; xru.u = *(const unsigned int*)(xr2 + (size_t)node * 128 + lane * 2);
    float2 wf = ((const float2*)att2)[lane];
    const f16x2 w2 = {(f16)wf.x, (f16)wf.y};
    const f16x2 c02 = {(f16)0.2f, (f16)0.2f};

    const int beg = row_start[node], end = row_start[node + 1];
    float l = 0.f, acc0 = 0.f, acc1 = 0.f;

    if (beg < end) {
        const int last = end - 1;
        uh c[4];
        #pragma unroll
        for (int k = 0; k < 4; ++k)
            c[k].u = *(const unsigned int*)(xl2 + (size_t)ssrc[min(beg + k, last)] * 128 + lane * 2);

        for (int p = beg; p < end; p += 4) {
            uh nx[4];
            #pragma unroll
            for (int k = 0; k < 4; ++k)
                nx[k].u = *(const unsigned int*)(xl2 + (size_t)ssrc[min(p + 4 + k, last)] * 128 + lane * 2);

            float sc[4];
            #pragma unroll
            for (int k = 0; k < 4; ++k) {
                f16x2 v = c[k].h + xru.h;
                f16x2 lr = __builtin_elementwise_max(v, v * c02);
                sc[k] = __builtin_amdgcn_fdot2(lr, w2, 0.f, false);
            }
            #pragma unroll
            for (int k = 0; k < 4; ++k) {
                #pragma unroll
                for (int off = 1; off < 64; off <<= 1) sc[k] += __shfl_xor(sc[k], off);
            }
            #pragma unroll
            for (int k = 0; k < 4; ++k) {
                float pv = (p + k < end) ? __expf(sc[k]) : 0.f;
                l += pv;
                acc0 = fmaf(pv, (float)c[k].h[0], acc0);
                acc1 = fmaf(pv, (float)c[k].h[1], acc1);
            }
            #pragma unroll
            for (int k = 0; k < 4; ++k) c[k] = nx[k];
        }
    }

    float inv = 1.f / (l + 1e-16f);
    int c0i = lane * 2, c1i = lane * 2 + 1;
    float h0 = fmaf(acc0, inv, bias2[c0i]);
    float h1v = fmaf(acc1, inv, bias2[c1i]);
    float a = h0 * Wa[c0i] + h1v * Wa[c1i];
    float r = h0 * Wrc[c0i] + h1v * Wrc[c1i];
    #pragma unroll
    for (int off = 1; off < 64; off <<= 1) {
        a += __shfl_xor(a, off);
        r += __shfl_xor(r, off);
    }
    if (lane == 0) {
        out[node]     = 1.f / (1.f + __expf(-(a + ba[0])));
        out[n + node] = 1.f / (1.f + __expf(-(r + brc[0])));
    }
}

// ---------------------------------------------------------------------------
extern "C" void kernel_launch(void* const* d_in, const int* in_sizes, int n_in,
                              void* d_out, int out_size, void* d_ws, size_t ws_size,
                              hipStream_t stream) {
    const float* x    = (const float*)d_in[0];
    const int* ei     = (const int*)d_in[1];
    const float* W1l  = (const float*)d_in[2];
    const float* b1l  = (const float*)d_in[3];
    const float* W1r  = (const float*)d_in[4];
    const float* b1r  = (const float*)d_in[5];
    const float* att1 = (const float*)d_in[6];
    const float* bias1= (const float*)d_in[7];
    const float* W2l  = (const float*)d_in[8];
    const float* b2l  = (const float*)d_in[9];
    const float* W2r  = (const float*)d_in[10];
    const float* b2r  = (const float*)d_in[11];
    const float* att2 = (const float*)d_in[12];
    const float* bias2= (const float*)d_in[13];
    const float* Wa   = (const float*)d_in[14];
    const float* ba   = (const float*)d_in[15];
    const float* Wrc  = (const float*)d_in[16];
    const float* brc  = (const float*)d_in[17];
    float* out = (float*)d_out;

    const int N = N_NODES, E = N_EDGES;
    const int* src = ei;
    const int* dst = ei + E;

    char* ws = (char*)d_ws;
    u16*   xl1  = (u16*)ws;                           // [MPAD][512] f16 = 20,578,304
    u16*   xr1  = (u16*)(ws + 20578304);              // [MPAD][512] f16 = 20,578,304
    u16*   h1b  = (u16*)(ws + 41156608);              // [MPAD][512] f16 = 20,578,304
    u16*   xb   = (u16*)(ws + 61734912);              // [MPAD][256] f16 = 10,289,152
    u16*   xl2  = (u16*)(ws + 61734912);              // [MPAD][128] reuses xb (gemm2)
    u16*   xr2  = (u16*)(ws + 61734912 + 5144576);    // [MPAD][128]
    u16*   BT1  = (u16*)(ws + 72024064);              // [1024][256] f16 = 524,288
    u16*   BT2  = (u16*)(ws + 72548352);              // [256][512] f16 = 262,144
    float* bc1  = (float*)(ws + 72810496);            // 4096
    float* bc2  = (float*)(ws + 72814592);            // 1024
    int* deg       = (int*)(ws + 72815616);           // 80,000
    int* row_start = (int*)(ws + 72896000);           // 80,004
    int* cursor    = (int*)(ws + 72976128);           // 80,000
    int* ssrc      = (int*)(ws + 73056128);           // 1,280,000
    int* seid      = (int*)(ws + 74336128);           // 1,280,000
    int* sdst      = (int*)(ws + 75616128);           // 1,280,000
    // end ~76.9 MB (89.8 MB proven available)

    // --- CSR build (deterministic via parallel rank) ---
    hipMemsetAsync(deg, 0, N * sizeof(int), stream);
    hist_kernel<<<(E + 255) / 256, 256, 0, stream>>>(dst, deg, E);
    scan_kernel<<<1, 1024, 0, stream>>>(deg, row_start, cursor, N);
    scatter_kernel<<<(E + 255) / 256, 256, 0, stream>>>(dst, cursor, seid, sdst, E);
    rank_kernel<<<(E + 255) / 256, 256, 0, stream>>>(row_start, seid, sdst, src, ssrc, E);

    // --- casts / weight prep ---
    cast_x_kernel<<<(MPAD * IN_DIM / 4 + 255) / 256, 256, 0, stream>>>(x, xb);
    transpose_all_kernel<<<dim3(16, 16, 4), dim3(32, 8), 0, stream>>>(
        W1l, W1r, W2l, W2r, BT1, BT2);
    prep_bias_kernel<<<1, 1024, 0, stream>>>(b1l, b1r, b2l, b2r, bc1, bc2);

    // --- layer 1: GEMM writes split xl1|xr1, then fused edge phase ---
    gemm_f16_kernel<<<157 * 8, 256, 0, stream>>>(xb, BT1, bc1, xl1, xr1, 256, 512, 8);
    fused1_kernel<<<(N + 3) / 4, 256, 0, stream>>>(xl1, xr1, row_start, ssrc,
                                                   att1, bias1, h1b, N);

    // --- layer 2 + heads: GEMM writes split xl2|xr2 ---
    gemm_f16_kernel<<<157 * 2, 256, 0, stream>>>(h1b, BT2, bc2, xl2, xr2, 512, 128, 2);
    fused2_kernel<<<(N + 3) / 4, 256, 0, stream>>>(xl2, xr2, row_start, ssrc, att2, bias2,
                                                   Wa, ba, Wrc, brc, out, N);
}

// Round 21
// 217.740 us; speedup vs baseline: 1.0482x; 1.0029x over previous
//
#include <hip/hip_runtime.h>
#include <hip/hip_bf16.h>
#include <hip/hip_fp16.h>

#define N_NODES 20000
#define N_EDGES 320000
#define IN_DIM 256
#define HID 128
#define HEADS 4
#define MPAD 20096   // 157 * 128

typedef unsigned short u16;
typedef _Float16 f16;
typedef __attribute__((ext_vector_type(2))) _Float16 f16x2;
typedef __attribute__((ext_vector_type(8))) _Float16 f16x8;
typedef __attribute__((ext_vector_type(4))) float f32x4;
typedef __attribute__((address_space(1))) void g_void;
typedef __attribute__((address_space(3))) void l_void;

__device__ __forceinline__ u16 f2h16(float f) {
    union { f16 h; u16 u; } c; c.h = (f16)f; return c.u;   // v_cvt_f16_f32, RNE
}
// bijective XCD swizzle (m204)
__device__ __forceinline__ int xcd_swz(int orig, int nwg) {
    int q = nwg >> 3, r = nwg & 7;
    int xcd = orig & 7, lin = orig >> 3;
    return (xcd < r ? xcd * (q + 1) : r * (q + 1) + (xcd - r) * q) + lin;
}

// ---------------------------------------------------------------------------
// CSR build: histogram -> scan -> scatter(eid,dst) -> parallel rank+fill
// Deterministic: final ssrc order within each segment is ascending edge id.
// ---------------------------------------------------------------------------
__global__ void hist_kernel(const int* __restrict__ dst, int* __restrict__ deg, int E) {
    int i = blockIdx.x * blockDim.x + threadIdx.x;
    if (i < E) atomicAdd(&deg[dst[i]], 1);
}

__global__ __launch_bounds__(1024) void scan_kernel(
    const int* __restrict__ deg, int* __restrict__ row_start,
    int* __restrict__ cursor, int n) {
    __shared__ int partial[1024];
    int t = threadIdx.x;
    int chunk = (n + 1023) / 1024;
    int begin = t * chunk;
    int end = min(begin + chunk, n);
    int s = 0;
    for (int i = begin; i < end; ++i) s += deg[i];
    partial[t] = s;
    __syncthreads();
    for (int off = 1; off < 1024; off <<= 1) {
        int v = (t >= off) ? partial[t - off] : 0;
        __syncthreads();
        partial[t] += v;
        __syncthreads();
    }
    int run = (t == 0) ? 0 : partial[t - 1];
    for (int i = begin; i < end; ++i) {
        row_start[i] = run;
        cursor[i] = run;
        run += deg[i];
    }
    if (t == 1023) row_start[n] = run;
}

__global__ void scatter_kernel(const int* __restrict__ dst, int* __restrict__ cursor,
                               int* __restrict__ seid, int* __restrict__ sdst, int E) {
    int i = blockIdx.x * blockDim.x + threadIdx.x;
    if (i < E) {
        int d = dst[i];
        int pos = atomicAdd(&cursor[d], 1);
        seid[pos] = i;
        sdst[pos] = d;
    }
}

__global__ void rank_kernel(const int* __restrict__ row_start, const int* __restrict__ seid,
                            const int* __restrict__ sdst, const int* __restrict__ src,
                            int* __restrict__ ssrc, int E) {
    int i = blockIdx.x * blockDim.x + threadIdx.x;
    if (i >= E) return;
    int d = sdst[i];
    int beg = row_start[d], end = row_start[d + 1];
    int my = seid[i];
    int rank = 0;
    for (int j = beg; j < end; ++j) rank += (seid[j] < my) ? 1 : 0;
    ssrc[beg + rank] = src[my];
}

// ---------------------------------------------------------------------------
// cast x (fp32 [20000][256]) -> f16 [MPAD][256], pad rows zeroed
// ---------------------------------------------------------------------------
__global__ void cast_x_kernel(const float* __restrict__ x, u16* __restrict__ xb) {
    int i = blockIdx.x * blockDim.x + threadIdx.x;     // quad id
    const int nq = MPAD * IN_DIM / 4;
    if (i >= nq) return;
    int elem = i * 4;
    uint2 u;
    if (elem < N_NODES * IN_DIM) {
        float4 v = ((const float4*)x)[i];
        u.x = (unsigned)f2h16(v.x) | ((unsigned)f2h16(v.y) << 16);
        u.y = (unsigned)f2h16(v.z) | ((unsigned)f2h16(v.w) << 16);
    } else {
        u.x = 0u; u.y = 0u;
    }
    *(uint2*)(xb + elem) = u;
}

// ---------------------------------------------------------------------------
// transpose+cast all four weights: W fp32 [K][N] -> out f16 [N][K]
// ---------------------------------------------------------------------------
__global__ __launch_bounds__(256) void transpose_all_kernel(
    const float* __restrict__ W1l, const float* __restrict__ W1r,
    const float* __restrict__ W2l, const float* __restrict__ W2r,
    u16* __restrict__ BT1, u16* __restrict__ BT2) {
    const float* W; u16* out; int K, N;
    switch (blockIdx.z) {
        case 0:  W = W1l; out = BT1;             K = 256; N = 512; break;
        case 1:  W = W1r; out = BT1 + 512 * 256; K = 256; N = 512; break;
        case 2:  W = W2l; out = BT2;             K = 512; N = 128; break;
        default: W = W2r; out = BT2 + 128 * 512; K = 512; N = 128; break;
    }
    int bx = blockIdx.x * 32;   // n base
    int by = blockIdx.y * 32;   // k base
    if (bx >= N || by >= K) return;
    __shared__ float t[32][33];
    int tx = threadIdx.x, ty = threadIdx.y;
    #pragma unroll
    for (int j = 0; j < 32; j += 8)
        t[ty + j][tx] = W[(size_t)(by + ty + j) * N + bx + tx];
    __syncthreads();
    #pragma unroll
    for (int j = 0; j < 32; j += 8)
        out[(size_t)(bx + ty + j) * K + by + tx] = f2h16(t[tx][ty + j]);
}

// ---------------------------------------------------------------------------
// concat biases (fp32)
// ---------------------------------------------------------------------------
__global__ void prep_bias_kernel(const float* b1l, const float* b1r,
                                 const float* b2l, const float* b2r,
                                 float* bc1, float* bc2) {
    int t = threadIdx.x;   // one block of 1024
    if (t < 512) bc1[t] = b1l[t];
    else bc1[t] = b1r[t - 512];
    if (t < 128) bc2[t] = b2l[t];
    else if (t < 256) bc2[t] = b2r[t - 128];
}

// ---------------------------------------------------------------------------
// f16 MFMA GEMM, BK=64 (4 barriers-pairs fewer), SPLIT OUTPUT:
// cols [0,halfN) -> Cl, [halfN,2*halfN) -> Cr, each [MPAD][halfN].
// 8-slot XOR k-swizzle: stage skk=(slot^(row&7))*8 (row&7 invariant over the
// 4 issue chunks since 32==0 mod 8); read fslot_t=((t*4+fg)^(fr&7))*8.
// MFMA order identical to BK=32 version -> bit-identical output.
// LDS 32 KB (As|Bs 16 KB each); epilogue reuses As region (16 KB).
// ---------------------------------------------------------------------------
__global__ __launch_bounds__(256) void gemm_f16_kernel(
    const u16* __restrict__ A, const u16* __restrict__ BT,
    const float* __restrict__ bias, u16* __restrict__ Cl, u16* __restrict__ Cr,
    int K, int halfN, int nbx) {
    __shared__ u16 smem[16384];          // As[8192] | Bs[8192]
    u16* As = smem;
    u16* Bs = smem + 8192;
    const int tid = threadIdx.x;
    const int lane = tid & 63;
    const int wid = tid >> 6;
    const int wr = wid >> 1, wc = wid & 1;
    const int wg = xcd_swz(blockIdx.x, gridDim.x);
    const int brow = (wg / nbx) * 128, bcol = (wg % nbx) * 128;

    // staging: issue i covers rows i*32 + (tid>>3), slot tid&7, 8 elems
    const int srow = tid >> 3;           // 0..31
    const int skk = ((tid & 7) ^ (srow & 7)) * 8;
    const u16* gaB = A + (size_t)(brow + srow) * K + skk;
    const u16* gbB = BT + (size_t)(bcol + srow) * K + skk;

    // fragment read bases: row stride 64 elems; sub-step slots
    const int fr = lane & 15;
    const int fg = lane >> 4;
    const int fs0 = ((fg    ) ^ (fr & 7)) * 8;   // kgroups 0..3 (k 0..31)
    const int fs1 = ((4 + fg) ^ (fr & 7)) * 8;   // kgroups 4..7 (k 32..63)
    const u16* ra = As + (wr * 64 + fr) * 64;
    const u16* rb = Bs + (wc * 64 + fr) * 64;

    f32x4 acc[4][4];
    #pragma unroll
    for (int m = 0; m < 4; ++m)
        #pragma unroll
        for (int n = 0; n < 4; ++n)
            acc[m][n] = (f32x4){0.f, 0.f, 0.f, 0.f};

    for (int k0 = 0; k0 < K; k0 += 64) {
        #pragma unroll
        for (int i = 0; i < 4; ++i)
            __builtin_amdgcn_global_load_lds(
                (const g_void*)(gaB + (size_t)i * 32 * K + k0),
                (l_void*)(As + i * 2048 + tid * 8), 16, 0, 0);
        #pragma unroll
        for (int i = 0; i < 4; ++i)
            __builtin_amdgcn_global_load_lds(
                (const g_void*)(gbB + (size_t)i * 32 * K + k0),
                (l_void*)(Bs + i * 2048 + tid * 8), 16, 0, 0);
        __syncthreads();
        {
            f16x8 av[4], bv[4];
            #pragma unroll
            for (int m = 0; m < 4; ++m) av[m] = *(const f16x8*)(ra + m * 1024 + fs0);
            #pragma unroll
            for (int n = 0; n < 4; ++n) bv[n] = *(const f16x8*)(rb + n * 1024 + fs0);
            #pragma unroll
            for (int m = 0; m < 4; ++m)
                #pragma unroll
                for (int n = 0; n < 4; ++n)
                    acc[m][n] = __builtin_amdgcn_mfma_f32_16x16x32_f16(av[m], bv[n], acc[m][n], 0, 0, 0);
        }
        {
            f16x8 av[4], bv[4];
            #pragma unroll
            for (int m = 0; m < 4; ++m) av[m] = *(const f16x8*)(ra + m * 1024 + fs1);
            #pragma unroll
            for (int n = 0; n < 4; ++n) bv[n] = *(const f16x8*)(rb + n * 1024 + fs1);
            #pragma unroll
            for (int m = 0; m < 4; ++m)
                #pragma unroll
                for (int n = 0; n < 4; ++n)
                    acc[m][n] = __builtin_amdgcn_mfma_f32_16x16x32_f16(av[m], bv[n], acc[m][n], 0, 0, 0);
        }
        __syncthreads();
    }

    // output buffer select (whole tile is in one half)
    const bool right = (bcol >= halfN);
    u16* Cb = right ? Cr : Cl;
    const int cbase = bcol - (right ? halfN : 0);

    // epilogue: half-tile LDS repack (reuses As region), coalesced 16B stores.
    float bv4[4];
    #pragma unroll
    for (int n = 0; n < 4; ++n) bv4[n] = bias[bcol + wc * 64 + n * 16 + fr];
    #pragma unroll
    for (int ph = 0; ph < 2; ++ph) {
        __syncthreads();
        if (wr == ph) {
            #pragma unroll
            for (int m = 0; m < 4; ++m)
                #pragma unroll
                for (int n = 0; n < 4; ++n) {
                    const int cc = wc * 64 + n * 16 + fr;
                    #pragma unroll
                    for (int j = 0; j < 4; ++j) {
                        const int rr = m * 16 + fg * 4 + j;
                        smem[rr * 128 + (cc ^ (((rr >> 2) & 3) << 4))] =
                            f2h16(acc[m][n][j] + bv4[n]);
                    }
                }
        }
        __syncthreads();
        #pragma unroll
        for (int it = 0; it < 4; ++it) {
            const int rr = it * 16 + (tid >> 4);
            const int cc0 = (tid & 15) * 8;
            *(uint4*)(Cb + (size_t)(brow + ph * 64 + rr) * halfN + cbase + cc0) =
                *(const uint4*)(smem + rr * 128 + (cc0 ^ (((rr >> 2) & 3) << 4)));
        }
    }
}

// ---------------------------------------------------------------------------
// fused layer-1 edge phase: one wave per node, no-shift softmax, 4-edge
// BRANCHLESS unroll (f16 packed state). Clamped indices, pv=0
// neutralization, sequential sum order. fp32 accumulation.
// ---------------------------------------------------------------------------
__global__ __launch_bounds__(256) void fused1_kernel(
    const u16* __restrict__ xl, const u16* __restrict__ xr,
    const int* __restrict__ row_start, const int* __restrict__ ssrc,
    const float* __restrict__ att1, const float* __restrict__ bias1,
    u16* __restrict__ h1, int n) {
    int node = blockIdx.x * 4 + (threadIdx.x >> 6);
    int lane = threadIdx.x & 63;
    if (node >= n) return;

    f16x8 xrv = *(const f16x8*)(xr + (size_t)node * 512 + lane * 8);
    const f16x2* xrh = (const f16x2*)&xrv;
    float4 w0 = ((const float4*)att1)[lane * 2];
    float4 w1 = ((const float4*)att1)[lane * 2 + 1];
    f16x2 wa2[4];
    wa2[0] = (f16x2){(f16)w0.x, (f16)w0.y};
    wa2[1] = (f16x2){(f16)w0.z, (f16)w0.w};
    wa2[2] = (f16x2){(f16)w1.x, (f16)w1.y};
    wa2[3] = (f16x2){(f16)w1.z, (f16)w1.w};
    const f16x2 c02 = {(f16)0.2f, (f16)0.2f};

    int beg = row_start[node], end = row_start[node + 1];
    float l = 0.f;
    float acc[8] = {0.f, 0.f, 0.f, 0.f, 0.f, 0.f, 0.f, 0.f};

    if (beg < end) {
        const int last = end - 1;
        f16x8 c[4];
        #pragma unroll
        for (int k = 0; k < 4; ++k)
            c[k] = *(const f16x8*)(xl + (size_t)ssrc[min(beg + k, last)] * 512 + lane * 8);

        for (int p = beg; p < end; p += 4) {
            f16x8 nx[4];
            #pragma unroll
            for (int k = 0; k < 4; ++k)
                nx[k] = *(const f16x8*)(xl + (size_t)ssrc[min(p + 4 + k, last)] * 512 + lane * 8);

            float sc[4];
            #pragma unroll
            for (int k = 0; k < 4; ++k) {
                const f16x2* xh = (const f16x2*)&c[k];
                float s = 0.f;
                #pragma unroll
                for (int j = 0; j < 4; ++j) {
                    f16x2 v = xh[j] + xrh[j];
                    f16x2 lr = __builtin_elementwise_max(v, v * c02);
                    s = __builtin_amdgcn_fdot2(lr, wa2[j], s, false);
                }
                sc[k] = s;
            }
            #pragma unroll
            for (int k = 0; k < 4; ++k) {
                sc[k] += __shfl_xor(sc[k], 1);
                sc[k] += __shfl_xor(sc[k], 2);
                sc[k] += __shfl_xor(sc[k], 4);
                sc[k] += __shfl_xor(sc[k], 8);
            }
            #pragma unroll
            for (int k = 0; k < 4; ++k) {
                float pv = (p + k < end) ? __expf(sc[k]) : 0.f;
                l += pv;
                #pragma unroll
                for (int j = 0; j < 8; ++j) acc[j] = fmaf(pv, (float)c[k][j], acc[j]);
            }
            #pragma unroll
            for (int k = 0; k < 4; ++k) c[k] = nx[k];
        }
    }

    float inv = 1.f / (l + 1e-16f);
    float4 b0 = ((const float4*)bias1)[lane * 2];
    float4 b1 = ((const float4*)bias1)[lane * 2 + 1];
    float bb[8] = {b0.x, b0.y, b0.z, b0.w, b1.x, b1.y, b1.z, b1.w};
    u16 outb[8];
    #pragma unroll
    for (int j = 0; j < 8; ++j) {
        float v = fmaf(acc[j], inv, bb[j]);
        v = v > 0.f ? v : __expf(v) - 1.f;   // ELU
        outb[j] = f2h16(v);
    }
    *(uint4*)(h1 + (size_t)node * 512 + lane * 8) = *(const uint4*)outb;
}

// ---------------------------------------------------------------------------
// fused layer-2 edge phase + heads: one wave per node, no-shift softmax,
// 4-edge BRANCHLESS unroll. f16 packed score; fp32 accumulation.
// ---------------------------------------------------------------------------
__global__ __launch_bounds__(256) void fused2_kernel(
    const u16* __restrict__ xl2, const u16* __restrict__ xr2,
    const int* __restrict__ row_start, const int* __restrict__ ssrc,
    const float* __restrict__ att2, const float* __restrict__ bias2,
    const float* __restrict__ Wa, const float* __restrict__ ba,
    const float* __restrict__ Wrc, const float* __restrict__ brc,
    float* __restrict__ out, int n) {
    const int node = blockIdx.x * 4 + (threadIdx.x >> 6);
    const int lane = threadIdx.x & 63;
    if (node >= n) return;

    union uh { unsigned int u; f16x2 h; };
    uh xru; xru.u = *(const unsigned int*)(xr2 + (size_t)node * 128 + lane * 2);
    float2 wf = ((const float2*)att2)[lane];
    const f16x2 w2 = {(f16)wf.x, (f16)wf.y};
    const f16x2 c02 = {(f16)0.2f, (f16)0.2f};

    const int beg = row_start[node], end = row_start[node + 1];
    float l = 0.f, acc0 = 0.f, acc1 = 0.f;

    if (beg < end) {
        const int last = end - 1;
        uh c[4];
        #pragma unroll
        for (int k = 0; k < 4; ++k)
            c[k].u = *(const unsigned int*)(xl2 + (size_t)ssrc[min(beg + k, last)] * 128 + lane * 2);

        for (int p = beg; p < end; p += 4) {
            uh nx[4];
            #pragma unroll
            for (int k = 0; k < 4; ++k)
                nx[k].u = *(const unsigned int*)(xl2 + (size_t)ssrc[min(p + 4 + k, last)] * 128 + lane * 2);

            float sc[4];
            #pragma unroll
            for (int k = 0; k < 4; ++k) {
                f16x2 v = c[k].h + xru.h;
                f16x2 lr = __builtin_elementwise_max(v, v * c02);
                sc[k] = __builtin_amdgcn_fdot2(lr, w2, 0.f, false);
            }
            #pragma unroll
            for (int k = 0; k < 4; ++k) {
                #pragma unroll
                for (int off = 1; off < 64; off <<= 1) sc[k] += __shfl_xor(sc[k], off);
            }
            #pragma unroll
            for (int k = 0; k < 4; ++k) {
                float pv = (p + k < end) ? __expf(sc[k]) : 0.f;
                l += pv;
                acc0 = fmaf(pv, (float)c[k].h[0], acc0);
                acc1 = fmaf(pv, (float)c[k].h[1], acc1);
            }
            #pragma unroll
            for (int k = 0; k < 4; ++k) c[k] = nx[k];
        }
    }

    float inv = 1.f / (l + 1e-16f);
    int c0i = lane * 2, c1i = lane * 2 + 1;
    float h0 = fmaf(acc0, inv, bias2[c0i]);
    float h1v = fmaf(acc1, inv, bias2[c1i]);
    float a = h0 * Wa[c0i] + h1v * Wa[c1i];
    float r = h0 * Wrc[c0i] + h1v * Wrc[c1i];
    #pragma unroll
    for (int off = 1; off < 64; off <<= 1) {
        a += __shfl_xor(a, off);
        r += __shfl_xor(r, off);
    }
    if (lane == 0) {
        out[node]     = 1.f / (1.f + __expf(-(a + ba[0])));
        out[n + node] = 1.f / (1.f + __expf(-(r + brc[0])));
    }
}

// ---------------------------------------------------------------------------
extern "C" void kernel_launch(void* const* d_in, const int* in_sizes, int n_in,
                              void* d_out, int out_size, void* d_ws, size_t ws_size,
                              hipStream_t stream) {
    const float* x    = (const float*)d_in[0];
    const int* ei     = (const int*)d_in[1];
    const float* W1l  = (const float*)d_in[2];
    const float* b1l  = (const float*)d_in[3];
    const float* W1r  = (const float*)d_in[4];
    const float* b1r  = (const float*)d_in[5];
    const float* att1 = (const float*)d_in[6];
    const float* bias1= (const float*)d_in[7];
    const float* W2l  = (const float*)d_in[8];
    const float* b2l  = (const float*)d_in[9];
    const float* W2r  = (const float*)d_in[10];
    const float* b2r  = (const float*)d_in[11];
    const float* att2 = (const float*)d_in[12];
    const float* bias2= (const float*)d_in[13];
    const float* Wa   = (const float*)d_in[14];
    const float* ba   = (const float*)d_in[15];
    const float* Wrc  = (const float*)d_in[16];
    const float* brc  = (const float*)d_in[17];
    float* out = (float*)d_out;

    const int N = N_NODES, E = N_EDGES;
    const int* src = ei;
    const int* dst = ei + E;

    char* ws = (char*)d_ws;
    u16*   xl1  = (u16*)ws;                           // [MPAD][512] f16 = 20,578,304
    u16*   xr1  = (u16*)(ws + 20578304);              // [MPAD][512] f16 = 20,578,304
    u16*   h1b  = (u16*)(ws + 41156608);              // [MPAD][512] f16 = 20,578,304
    u16*   xb   = (u16*)(ws + 61734912);              // [MPAD][256] f16 = 10,289,152
    u16*   xl2  = (u16*)(ws + 61734912);              // [MPAD][128] reuses xb (gemm2)
    u16*   xr2  = (u16*)(ws + 61734912 + 5144576);    // [MPAD][128]
    u16*   BT1  = (u16*)(ws + 72024064);              // [1024][256] f16 = 524,288
    u16*   BT2  = (u16*)(ws + 72548352);              // [256][512] f16 = 262,144
    float* bc1  = (float*)(ws + 72810496);            // 4096
    float* bc2  = (float*)(ws + 72814592);            // 1024
    int* deg       = (int*)(ws + 72815616);           // 80,000
    int* row_start = (int*)(ws + 72896000);           // 80,004
    int* cursor    = (int*)(ws + 72976128);           // 80,000
    int* ssrc      = (int*)(ws + 73056128);           // 1,280,000
    int* seid      = (int*)(ws + 74336128);           // 1,280,000
    int* sdst      = (int*)(ws + 75616128);           // 1,280,000
    // end ~76.9 MB (89.8 MB proven available)

    // --- CSR build (deterministic via parallel rank) ---
    hipMemsetAsync(deg, 0, N * sizeof(int), stream);
    hist_kernel<<<(E + 255) / 256, 256, 0, stream>>>(dst, deg, E);
    scan_kernel<<<1, 1024, 0, stream>>>(deg, row_start, cursor, N);
    scatter_kernel<<<(E + 255) / 256, 256, 0, stream>>>(dst, cursor, seid, sdst, E);
    rank_kernel<<<(E + 255) / 256, 256, 0, stream>>>(row_start, seid, sdst, src, ssrc, E);

    // --- casts / weight prep ---
    cast_x_kernel<<<(MPAD * IN_DIM / 4 + 255) / 256, 256, 0, stream>>>(x, xb);
    transpose_all_kernel<<<dim3(16, 16, 4), dim3(32, 8), 0, stream>>>(
        W1l, W1r, W2l, W2r, BT1, BT2);
    prep_bias_kernel<<<1, 1024, 0, stream>>>(b1l, b1r, b2l, b2r, bc1, bc2);

    // --- layer 1: GEMM writes split xl1|xr1, then fused edge phase ---
    gemm_f16_kernel<<<157 * 8, 256, 0, stream>>>(xb, BT1, bc1, xl1, xr1, 256, 512, 8);
    fused1_kernel<<<(N + 3) / 4, 256, 0, stream>>>(xl1, xr1, row_start, ssrc,
                                                   att1, bias1, h1b, N);

    // --- layer 2 + heads: GEMM writes split xl2|xr2 ---
    gemm_f16_kernel<<<157 * 2, 256, 0, stream>>>(h1b, BT2, bc2, xl2, xr2, 512, 128, 2);
    fused2_kernel<<<(N + 3) / 4, 256, 0, stream>>>(xl2, xr2, row_start, ssrc, att2, bias2,
                                                   Wa, ba, Wrc, brc, out, N);
}

// Round 22
// 213.615 us; speedup vs baseline: 1.0685x; 1.0193x over previous
//
#include <hip/hip_runtime.h>
#include <hip/hip_bf16.h>
#include <hip/hip_fp16.h>

#define N_NODES 20000
#define N_EDGES 320000
#define IN_DIM 256
#define HID 128
#define HEADS 4
#define MPAD 20096   // 157 * 128

typedef unsigned short u16;
typedef _Float16 f16;
typedef __attribute__((ext_vector_type(2))) _Float16 f16x2;
typedef __attribute__((ext_vector_type(8))) _Float16 f16x8;
typedef __attribute__((ext_vector_type(4))) float f32x4;
typedef __attribute__((address_space(1))) void g_void;
typedef __attribute__((address_space(3))) void l_void;

__device__ __forceinline__ u16 f2h16(float f) {
    union { f16 h; u16 u; } c; c.h = (f16)f; return c.u;   // v_cvt_f16_f32, RNE
}
// bijective XCD swizzle (m204)
__device__ __forceinline__ int xcd_swz(int orig, int nwg) {
    int q = nwg >> 3, r = nwg & 7;
    int xcd = orig & 7, lin = orig >> 3;
    return (xcd < r ? xcd * (q + 1) : r * (q + 1) + (xcd - r) * q) + lin;
}

// ---------------------------------------------------------------------------
// merged prep: [0,5024) cast x->f16 | [5024,5408) weight transposes |
// [5408,6658) dst histogram | [6658] bias concat. All independent work.
// ---------------------------------------------------------------------------
#define NB_CAST 5024          // MPAD*256/4/256
#define NB_T    384           // 128+128+64+64
#define NB_HIST 1250          // (E+255)/256
#define NB_PREP (NB_CAST + NB_T + NB_HIST + 1)

__global__ __launch_bounds__(256) void prep_kernel(
    const float* __restrict__ x, u16* __restrict__ xb,
    const float* __restrict__ W1l, const float* __restrict__ W1r,
    const float* __restrict__ W2l, const float* __restrict__ W2r,
    u16* __restrict__ BT1, u16* __restrict__ BT2,
    const float* __restrict__ b1l, const float* __restrict__ b1r,
    const float* __restrict__ b2l, const float* __restrict__ b2r,
    float* __restrict__ bc1, float* __restrict__ bc2,
    const int* __restrict__ dst, int* __restrict__ deg, int E) {
    __shared__ float t[32][33];
    const int tid = threadIdx.x;
    const int bid = blockIdx.x;

    if (bid < NB_CAST) {
        // ---- cast x (fp32 [20000][256]) -> f16 [MPAD][256], pad zeroed ----
        int i = bid * 256 + tid;                  // quad id
        int elem = i * 4;
        uint2 u;
        if (elem < N_NODES * IN_DIM) {
            float4 v = ((const float4*)x)[i];
            u.x = (unsigned)f2h16(v.x) | ((unsigned)f2h16(v.y) << 16);
            u.y = (unsigned)f2h16(v.z) | ((unsigned)f2h16(v.w) << 16);
        } else {
            u.x = 0u; u.y = 0u;
        }
        if (elem < MPAD * IN_DIM) *(uint2*)(xb + elem) = u;
        return;
    }
    if (bid < NB_CAST + NB_T) {
        // ---- transpose+cast W fp32 [K][N] -> f16 [N][K] ----
        int b = bid - NB_CAST;
        const float* W; u16* out; int K, N;
        if (b < 128)      { W = W1l; out = BT1;             K = 256; N = 512; }
        else if (b < 256) { b -= 128; W = W1r; out = BT1 + 512 * 256; K = 256; N = 512; }
        else if (b < 320) { b -= 256; W = W2l; out = BT2;             K = 512; N = 128; }
        else              { b -= 320; W = W2r; out = BT2 + 128 * 512; K = 512; N = 128; }
        const int nbx = N / 32;
        const int bx = (b % nbx) * 32;
        const int by = (b / nbx) * 32;
        const int tx = tid & 31, ty = tid >> 5;   // (32,8)
        #pragma unroll
        for (int j = 0; j < 32; j += 8)
            t[ty + j][tx] = W[(size_t)(by + ty + j) * N + bx + tx];
        __syncthreads();
        #pragma unroll
        for (int j = 0; j < 32; j += 8)
            out[(size_t)(bx + ty + j) * K + by + tx] = f2h16(t[tx][ty + j]);
        return;
    }
    if (bid < NB_CAST + NB_T + NB_HIST) {
        // ---- dst histogram ----
        int i = (bid - NB_CAST - NB_T) * 256 + tid;
        if (i < E) atomicAdd(&deg[dst[i]], 1);
        return;
    }
    // ---- bias concat (single block) ----
    for (int q = tid; q < 1024; q += 256)
        bc1[q] = (q < 512) ? b1l[q] : b1r[q - 512];
    if (tid < 128) bc2[tid] = b2l[tid];
    else if (tid < 256) bc2[tid] = b2r[tid - 128];
}

// ---------------------------------------------------------------------------
// CSR: scan -> scatter(eid,dst) -> parallel rank+fill (deterministic)
// ---------------------------------------------------------------------------
__global__ __launch_bounds__(1024) void scan_kernel(
    const int* __restrict__ deg, int* __restrict__ row_start,
    int* __restrict__ cursor, int n) {
    __shared__ int partial[1024];
    int t = threadIdx.x;
    int chunk = (n + 1023) / 1024;
    int begin = t * chunk;
    int end = min(begin + chunk, n);
    int s = 0;
    for (int i = begin; i < end; ++i) s += deg[i];
    partial[t] = s;
    __syncthreads();
    for (int off = 1; off < 1024; off <<= 1) {
        int v = (t >= off) ? partial[t - off] : 0;
        __syncthreads();
        partial[t] += v;
        __syncthreads();
    }
    int run = (t == 0) ? 0 : partial[t - 1];
    for (int i = begin; i < end; ++i) {
        row_start[i] = run;
        cursor[i] = run;
        run += deg[i];
    }
    if (t == 1023) row_start[n] = run;
}

__global__ void scatter_kernel(const int* __restrict__ dst, int* __restrict__ cursor,
                               int* __restrict__ seid, int* __restrict__ sdst, int E) {
    int i = blockIdx.x * blockDim.x + threadIdx.x;
    if (i < E) {
        int d = dst[i];
        int pos = atomicAdd(&cursor[d], 1);
        seid[pos] = i;
        sdst[pos] = d;
    }
}

__global__ void rank_kernel(const int* __restrict__ row_start, const int* __restrict__ seid,
                            const int* __restrict__ sdst, const int* __restrict__ src,
                            int* __restrict__ ssrc, int E) {
    int i = blockIdx.x * blockDim.x + threadIdx.x;
    if (i >= E) return;
    int d = sdst[i];
    int beg = row_start[d], end = row_start[d + 1];
    int my = seid[i];
    int rank = 0;
    for (int j = beg; j < end; ++j) rank += (seid[j] < my) ? 1 : 0;
    ssrc[beg + rank] = src[my];
}

// ---------------------------------------------------------------------------
// f16 MFMA GEMM, BK=64, SPLIT OUTPUT (cols [0,halfN)->Cl, rest->Cr).
// 8-slot XOR k-swizzle; LDS 32 KB; epilogue reuses As; XCD swizzle.
// ---------------------------------------------------------------------------
__global__ __launch_bounds__(256) void gemm_f16_kernel(
    const u16* __restrict__ A, const u16* __restrict__ BT,
    const float* __restrict__ bias, u16* __restrict__ Cl, u16* __restrict__ Cr,
    int K, int halfN, int nbx) {
    __shared__ u16 smem[16384];          // As[8192] | Bs[8192]
    u16* As = smem;
    u16* Bs = smem + 8192;
    const int tid = threadIdx.x;
    const int lane = tid & 63;
    const int wid = tid >> 6;
    const int wr = wid >> 1, wc = wid & 1;
    const int wg = xcd_swz(blockIdx.x, gridDim.x);
    const int brow = (wg / nbx) * 128, bcol = (wg % nbx) * 128;

    const int srow = tid >> 3;           // 0..31
    const int skk = ((tid & 7) ^ (srow & 7)) * 8;
    const u16* gaB = A + (size_t)(brow + srow) * K + skk;
    const u16* gbB = BT + (size_t)(bcol + srow) * K + skk;

    const int fr = lane & 15;
    const int fg = lane >> 4;
    const int fs0 = ((fg    ) ^ (fr & 7)) * 8;
    const int fs1 = ((4 + fg) ^ (fr & 7)) * 8;
    const u16* ra = As + (wr * 64 + fr) * 64;
    const u16* rb = Bs + (wc * 64 + fr) * 64;

    f32x4 acc[4][4];
    #pragma unroll
    for (int m = 0; m < 4; ++m)
        #pragma unroll
        for (int n = 0; n < 4; ++n)
            acc[m][n] = (f32x4){0.f, 0.f, 0.f, 0.f};

    for (int k0 = 0; k0 < K; k0 += 64) {
        #pragma unroll
        for (int i = 0; i < 4; ++i)
            __builtin_amdgcn_global_load_lds(
                (const g_void*)(gaB + (size_t)i * 32 * K + k0),
                (l_void*)(As + i * 2048 + tid * 8), 16, 0, 0);
        #pragma unroll
        for (int i = 0; i < 4; ++i)
            __builtin_amdgcn_global_load_lds(
                (const g_void*)(gbB + (size_t)i * 32 * K + k0),
                (l_void*)(Bs + i * 2048 + tid * 8), 16, 0, 0);
        __syncthreads();
        {
            f16x8 av[4], bv[4];
            #pragma unroll
            for (int m = 0; m < 4; ++m) av[m] = *(const f16x8*)(ra + m * 1024 + fs0);
            #pragma unroll
            for (int n = 0; n < 4; ++n) bv[n] = *(const f16x8*)(rb + n * 1024 + fs0);
            #pragma unroll
            for (int m = 0; m < 4; ++m)
                #pragma unroll
                for (int n = 0; n < 4; ++n)
                    acc[m][n] = __builtin_amdgcn_mfma_f32_16x16x32_f16(av[m], bv[n], acc[m][n], 0, 0, 0);
        }
        {
            f16x8 av[4], bv[4];
            #pragma unroll
            for (int m = 0; m < 4; ++m) av[m] = *(const f16x8*)(ra + m * 1024 + fs1);
            #pragma unroll
            for (int n = 0; n < 4; ++n) bv[n] = *(const f16x8*)(rb + n * 1024 + fs1);
            #pragma unroll
            for (int m = 0; m < 4; ++m)
                #pragma unroll
                for (int n = 0; n < 4; ++n)
                    acc[m][n] = __builtin_amdgcn_mfma_f32_16x16x32_f16(av[m], bv[n], acc[m][n], 0, 0, 0);
        }
        __syncthreads();
    }

    const bool right = (bcol >= halfN);
    u16* Cb = right ? Cr : Cl;
    const int cbase = bcol - (right ? halfN : 0);

    float bv4[4];
    #pragma unroll
    for (int n = 0; n < 4; ++n) bv4[n] = bias[bcol + wc * 64 + n * 16 + fr];
    #pragma unroll
    for (int ph = 0; ph < 2; ++ph) {
        __syncthreads();
        if (wr == ph) {
            #pragma unroll
            for (int m = 0; m < 4; ++m)
                #pragma unroll
                for (int n = 0; n < 4; ++n) {
                    const int cc = wc * 64 + n * 16 + fr;
                    #pragma unroll
                    for (int j = 0; j < 4; ++j) {
                        const int rr = m * 16 + fg * 4 + j;
                        smem[rr * 128 + (cc ^ (((rr >> 2) & 3) << 4))] =
                            f2h16(acc[m][n][j] + bv4[n]);
                    }
                }
        }
        __syncthreads();
        #pragma unroll
        for (int it = 0; it < 4; ++it) {
            const int rr = it * 16 + (tid >> 4);
            const int cc0 = (tid & 15) * 8;
            *(uint4*)(Cb + (size_t)(brow + ph * 64 + rr) * halfN + cbase + cc0) =
                *(const uint4*)(smem + rr * 128 + (cc0 ^ (((rr >> 2) & 3) << 4)));
        }
    }
}

// ---------------------------------------------------------------------------
// fused layer-1 edge phase: one wave per node, no-shift softmax, 4-edge
// branchless unroll (f16 packed). Clamped indices, pv=0 neutralization.
// ---------------------------------------------------------------------------
__global__ __launch_bounds__(256) void fused1_kernel(
    const u16* __restrict__ xl, const u16* __restrict__ xr,
    const int* __restrict__ row_start, const int* __restrict__ ssrc,
    const float* __restrict__ att1, const float* __restrict__ bias1,
    u16* __restrict__ h1, int n) {
    int node = blockIdx.x * 4 + (threadIdx.x >> 6);
    int lane = threadIdx.x & 63;
    if (node >= n) return;

    f16x8 xrv = *(const f16x8*)(xr + (size_t)node * 512 + lane * 8);
    const f16x2* xrh = (const f16x2*)&xrv;
    float4 w0 = ((const float4*)att1)[lane * 2];
    float4 w1 = ((const float4*)att1)[lane * 2 + 1];
    f16x2 wa2[4];
    wa2[0] = (f16x2){(f16)w0.x, (f16)w0.y};
    wa2[1] = (f16x2){(f16)w0.z, (f16)w0.w};
    wa2[2] = (f16x2){(f16)w1.x, (f16)w1.y};
    wa2[3] = (f16x2){(f16)w1.z, (f16)w1.w};
    const f16x2 c02 = {(f16)0.2f, (f16)0.2f};

    int beg = row_start[node], end = row_start[node + 1];
    float l = 0.f;
    float acc[8] = {0.f, 0.f, 0.f, 0.f, 0.f, 0.f, 0.f, 0.f};

    if (beg < end) {
        const int last = end - 1;
        f16x8 c[4];
        #pragma unroll
        for (int k = 0; k < 4; ++k)
            c[k] = *(const f16x8*)(xl + (size_t)ssrc[min(beg + k, last)] * 512 + lane * 8);

        for (int p = beg; p < end; p += 4) {
            f16x8 nx[4];
            #pragma unroll
            for (int k = 0; k < 4; ++k)
                nx[k] = *(const f16x8*)(xl + (size_t)ssrc[min(p + 4 + k, last)] * 512 + lane * 8);

            float sc[4];
            #pragma unroll
            for (int k = 0; k < 4; ++k) {
                const f16x2* xh = (const f16x2*)&c[k];
                float s = 0.f;
                #pragma unroll
                for (int j = 0; j < 4; ++j) {
                    f16x2 v = xh[j] + xrh[j];
                    f16x2 lr = __builtin_elementwise_max(v, v * c02);
                    s = __builtin_amdgcn_fdot2(lr, wa2[j], s, false);
                }
                sc[k] = s;
            }
            #pragma unroll
            for (int k = 0; k < 4; ++k) {
                sc[k] += __shfl_xor(sc[k], 1);
                sc[k] += __shfl_xor(sc[k], 2);
                sc[k] += __shfl_xor(sc[k], 4);
                sc[k] += __shfl_xor(sc[k], 8);
            }
            #pragma unroll
            for (int k = 0; k < 4; ++k) {
                float pv = (p + k < end) ? __expf(sc[k]) : 0.f;
                l += pv;
                #pragma unroll
                for (int j = 0; j < 8; ++j) acc[j] = fmaf(pv, (float)c[k][j], acc[j]);
            }
            #pragma unroll
            for (int k = 0; k < 4; ++k) c[k] = nx[k];
        }
    }

    float inv = 1.f / (l + 1e-16f);
    float4 b0 = ((const float4*)bias1)[lane * 2];
    float4 b1 = ((const float4*)bias1)[lane * 2 + 1];
    float bb[8] = {b0.x, b0.y, b0.z, b0.w, b1.x, b1.y, b1.z, b1.w};
    u16 outb[8];
    #pragma unroll
    for (int j = 0; j < 8; ++j) {
        float v = fmaf(acc[j], inv, bb[j]);
        v = v > 0.f ? v : __expf(v) - 1.f;   // ELU
        outb[j] = f2h16(v);
    }
    *(uint4*)(h1 + (size_t)node * 512 + lane * 8) = *(const uint4*)outb;
}

// ---------------------------------------------------------------------------
// fused layer-2 edge phase + heads: one wave per node, no-shift softmax,
// 4-edge branchless unroll. f16 packed score; fp32 accumulation.
// ---------------------------------------------------------------------------
__global__ __launch_bounds__(256) void fused2_kernel(
    const u16* __restrict__ xl2, const u16* __restrict__ xr2,
    const int* __restrict__ row_start, const int* __restrict__ ssrc,
    const float* __restrict__ att2, const float* __restrict__ bias2,
    const float* __restrict__ Wa, const float* __restrict__ ba,
    const float* __restrict__ Wrc, const float* __restrict__ brc,
    float* __restrict__ out, int n) {
    const int node = blockIdx.x * 4 + (threadIdx.x >> 6);
    const int lane = threadIdx.x & 63;
    if (node >= n) return;

    union uh { unsigned int u; f16x2 h; };
    uh xru; xru.u = *(const unsigned int*)(xr2 + (size_t)node * 128 + lane * 2);
    float2 wf = ((const float2*)att2)[lane];
    const f16x2 w2 = {(f16)wf.x, (f16)wf.y};
    const f16x2 c02 = {(f16)0.2f, (f16)0.2f};

    const int beg = row_start[node], end = row_start[node + 1];
    float l = 0.f, acc0 = 0.f, acc1 = 0.f;

    if (beg < end) {
        const int last = end - 1;
        uh c[4];
        #pragma unroll
        for (int k = 0; k < 4; ++k)
            c[k].u = *(const unsigned int*)(xl2 + (size_t)ssrc[min(beg + k, last)] * 128 + lane * 2);

        for (int p = beg; p < end; p += 4) {
            uh nx[4];
            #pragma unroll
            for (int k = 0; k < 4; ++k)
                nx[k].u = *(const unsigned int*)(xl2 + (size_t)ssrc[min(p + 4 + k, last)] * 128 + lane * 2);

            float sc[4];
            #pragma unroll
            for (int k = 0; k < 4; ++k) {
                f16x2 v = c[k].h + xru.h;
                f16x2 lr = __builtin_elementwise_max(v, v * c02);
                sc[k] = __builtin_amdgcn_fdot2(lr, w2, 0.f, false);
            }
            #pragma unroll
            for (int k = 0; k < 4; ++k) {
                #pragma unroll
                for (int off = 1; off < 64; off <<= 1) sc[k] += __shfl_xor(sc[k], off);
            }
            #pragma unroll
            for (int k = 0; k < 4; ++k) {
                float pv = (p + k < end) ? __expf(sc[k]) : 0.f;
                l += pv;
                acc0 = fmaf(pv, (float)c[k].h[0], acc0);
                acc1 = fmaf(pv, (float)c[k].h[1], acc1);
            }
            #pragma unroll
            for (int k = 0; k < 4; ++k) c[k] = nx[k];
        }
    }

    float inv = 1.f / (l + 1e-16f);
    int c0i = lane * 2, c1i = lane * 2 + 1;
    float h0 = fmaf(acc0, inv, bias2[c0i]);
    float h1v = fmaf(acc1, inv, bias2[c1i]);
    float a = h0 * Wa[c0i] + h1v * Wa[c1i];
    float r = h0 * Wrc[c0i] + h1v * Wrc[c1i];
    #pragma unroll
    for (int off = 1; off < 64; off <<= 1) {
        a += __shfl_xor(a, off);
        r += __shfl_xor(r, off);
    }
    if (lane == 0) {
        out[node]     = 1.f / (1.f + __expf(-(a + ba[0])));
        out[n + node] = 1.f / (1.f + __expf(-(r + brc[0])));
    }
}

// ---------------------------------------------------------------------------
extern "C" void kernel_launch(void* const* d_in, const int* in_sizes, int n_in,
                              void* d_out, int out_size, void* d_ws, size_t ws_size,
                              hipStream_t stream) {
    const float* x    = (const float*)d_in[0];
    const int* ei     = (const int*)d_in[1];
    const float* W1l  = (const float*)d_in[2];
    const float* b1l  = (const float*)d_in[3];
    const float* W1r  = (const float*)d_in[4];
    const float* b1r  = (const float*)d_in[5];
    const float* att1 = (const float*)d_in[6];
    const float* bias1= (const float*)d_in[7];
    const float* W2l  = (const float*)d_in[8];
    const float* b2l  = (const float*)d_in[9];
    const float* W2r  = (const float*)d_in[10];
    const float* b2r  = (const float*)d_in[11];
    const float* att2 = (const float*)d_in[12];
    const float* bias2= (const float*)d_in[13];
    const float* Wa   = (const float*)d_in[14];
    const float* ba   = (const float*)d_in[15];
    const float* Wrc  = (const float*)d_in[16];
    const float* brc  = (const float*)d_in[17];
    float* out = (float*)d_out;

    const int N = N_NODES, E = N_EDGES;
    const int* src = ei;
    const int* dst = ei + E;

    char* ws = (char*)d_ws;
    u16*   xl1  = (u16*)ws;                           // [MPAD][512] f16 = 20,578,304
    u16*   xr1  = (u16*)(ws + 20578304);              // [MPAD][512] f16 = 20,578,304
    u16*   h1b  = (u16*)(ws + 41156608);              // [MPAD][512] f16 = 20,578,304
    u16*   xb   = (u16*)(ws + 61734912);              // [MPAD][256] f16 = 10,289,152
    u16*   xl2  = (u16*)(ws + 61734912);              // [MPAD][128] reuses xb (gemm2)
    u16*   xr2  = (u16*)(ws + 61734912 + 5144576);    // [MPAD][128]
    u16*   BT1  = (u16*)(ws + 72024064);              // [1024][256] f16 = 524,288
    u16*   BT2  = (u16*)(ws + 72548352);              // [256][512] f16 = 262,144
    float* bc1  = (float*)(ws + 72810496);            // 4096
    float* bc2  = (float*)(ws + 72814592);            // 1024
    int* deg       = (int*)(ws + 72815616);           // 80,000
    int* row_start = (int*)(ws + 72896000);           // 80,004
    int* cursor    = (int*)(ws + 72976128);           // 80,000
    int* ssrc      = (int*)(ws + 73056128);           // 1,280,000
    int* seid      = (int*)(ws + 74336128);           // 1,280,000
    int* sdst      = (int*)(ws + 75616128);           // 1,280,000
    // end ~76.9 MB (89.8 MB proven available)

    // --- merged prep (cast_x | weight transposes | histogram | biases) ---
    hipMemsetAsync(deg, 0, N * sizeof(int), stream);
    prep_kernel<<<NB_PREP, 256, 0, stream>>>(
        x, xb, W1l, W1r, W2l, W2r, BT1, BT2,
        b1l, b1r, b2l, b2r, bc1, bc2, dst, deg, E);

    // --- CSR build (deterministic via parallel rank) ---
    scan_kernel<<<1, 1024, 0, stream>>>(deg, row_start, cursor, N);
    scatter_kernel<<<(E + 255) / 256, 256, 0, stream>>>(dst, cursor, seid, sdst, E);
    rank_kernel<<<(E + 255) / 256, 256, 0, stream>>>(row_start, seid, sdst, src, ssrc, E);

    // --- layer 1: GEMM writes split xl1|xr1, then fused edge phase ---
    gemm_f16_kernel<<<157 * 8, 256, 0, stream>>>(xb, BT1, bc1, xl1, xr1, 256, 512, 8);
    fused1_kernel<<<(N + 3) / 4, 256, 0, stream>>>(xl1, xr1, row_start, ssrc,
                                                   att1, bias1, h1b, N);

    // --- layer 2 + heads: GEMM writes split xl2|xr2 ---
    gemm_f16_kernel<<<157 * 2, 256, 0, stream>>>(h1b, BT2, bc2, xl2, xr2, 512, 128, 2);
    fused2_kernel<<<(N + 3) / 4, 256, 0, stream>>>(xl2, xr2, row_start, ssrc, att2, bias2,
                                                   Wa, ba, Wrc, brc, out, N);
}